// Round 7
// baseline (668.303 us; speedup 1.0000x reference)
//
#include <hip/hip_runtime.h>
#include <hip/hip_bf16.h>

#define BT 2048
#define T_SEQ 1024
#define DIM 1024
#define DINNER 2048
#define DSTATE 128
#define HEADDIM 64
#define NHEADS 32
#define CONVCH 2304
#define DINPROJ 4384
#define EPS_F 1e-5f
#define NCHUNK 16   // T_SEQ / 64

typedef __bf16 bf16x8 __attribute__((ext_vector_type(8)));
typedef float f32x4 __attribute__((ext_vector_type(4)));

__device__ __forceinline__ float b2f(unsigned short u) {
  union { unsigned int i; float f; } v; v.i = ((unsigned int)u) << 16; return v.f;
}
__device__ __forceinline__ unsigned short f2b(float f) {
  unsigned int x = __float_as_uint(f);
  return (unsigned short)((x + 0x7fffu + ((x >> 16) & 1u)) >> 16);
}

// ---------------- fp32 -> bf16 weight conversion ----------------
__global__ void cvt_k(const float* __restrict__ in, unsigned short* __restrict__ out, int n) {
  int i = (blockIdx.x * 256 + threadIdx.x) * 4;
  if (i < n) {
    float4 v = *(const float4*)(in + i);
    out[i + 0] = f2b(v.x);
    out[i + 1] = f2b(v.y);
    out[i + 2] = f2b(v.z);
    out[i + 3] = f2b(v.w);
  }
}

// ---------------- embed lookup ----------------
__global__ void embed_k(const int* __restrict__ x, const float* __restrict__ emb,
                        float* __restrict__ h, unsigned short* __restrict__ hb) {
  int t = blockIdx.x;
  int tok = x[t];
  int d = threadIdx.x;
#pragma unroll
  for (int j = 0; j < 4; ++j, d += 256) {
    float v = emb[(size_t)tok * DIM + d];
    h[(size_t)t * DIM + d] = v;
    hb[(size_t)t * DIM + d] = f2b(v);
  }
}

// ---------------- FLAT GEMM: C[M,N] = A[M,K] * Bw[N,K]^T (bf16, fp32 acc) -------------
// LDS-free: both MFMA operand frags are "16 rows x 16B contiguous" patterns in this
// layout -> direct global_load_dwordx4 into VGPRs. No barriers, no vmcnt(0) drains
// (the m97 structural stall), no bank conflicts. Cross-wave reuse via L1/L2.
// Register ping-pong prefetch -> compiler emits fine-grained vmcnt(N) waits.
template <int MODE, int TM, int TN>
__global__ __launch_bounds__(256) void gemm_flat(
    const unsigned short* __restrict__ A,
    const unsigned short* __restrict__ Bw,
    int M, int N, int K,
    unsigned short* __restrict__ Cout,
    float* __restrict__ aux,
    unsigned short* __restrict__ aux2) {
  constexpr int FM = TM / 32, FN = TN / 32;
  const int tid = threadIdx.x;
  const int lane = tid & 63;
  const int wave = tid >> 6;
  const int m0 = blockIdx.y * TM;
  const int n0 = blockIdx.x * TN;
  const int wm = (wave >> 1) * (TM / 2);
  const int wn = (wave & 1) * (TN / 2);
  const int quad = lane >> 4;
  const int r = lane & 15;

  // per-frag global row pointers (lane-resolved); advance by k0 in the loop
  const unsigned short* aP[FM];
  const unsigned short* bP[FN];
#pragma unroll
  for (int mt = 0; mt < FM; ++mt)
    aP[mt] = A + (size_t)(m0 + wm + mt * 16 + r) * K + quad * 8;
#pragma unroll
  for (int nt = 0; nt < FN; ++nt) {
    int rb = n0 + wn + nt * 16 + r; if (rb >= N) rb = N - 1;
    bP[nt] = Bw + (size_t)rb * K + quad * 8;
  }

  f32x4 acc[FM][FN];
#pragma unroll
  for (int i = 0; i < FM; ++i)
#pragma unroll
    for (int j = 0; j < FN; ++j) acc[i][j] = f32x4{0.f, 0.f, 0.f, 0.f};

  bf16x8 af[2][FM], bfr[2][FN];
#pragma unroll
  for (int mt = 0; mt < FM; ++mt) af[0][mt] = *(const bf16x8*)(aP[mt]);
#pragma unroll
  for (int nt = 0; nt < FN; ++nt) bfr[0][nt] = *(const bf16x8*)(bP[nt]);

  for (int k0 = 0; k0 < K; k0 += 64) {
    // prefetch k0+32 while computing k0
#pragma unroll
    for (int mt = 0; mt < FM; ++mt) af[1][mt] = *(const bf16x8*)(aP[mt] + k0 + 32);
#pragma unroll
    for (int nt = 0; nt < FN; ++nt) bfr[1][nt] = *(const bf16x8*)(bP[nt] + k0 + 32);
#pragma unroll
    for (int mt = 0; mt < FM; ++mt)
#pragma unroll
      for (int nt = 0; nt < FN; ++nt)
        acc[mt][nt] = __builtin_amdgcn_mfma_f32_16x16x32_bf16(af[0][mt], bfr[0][nt], acc[mt][nt], 0, 0, 0);
    // prefetch k0+64 while computing k0+32 (tail wraps to 0, discarded)
    const int kn = (k0 + 64 < K) ? k0 + 64 : 0;
#pragma unroll
    for (int mt = 0; mt < FM; ++mt) af[0][mt] = *(const bf16x8*)(aP[mt] + kn);
#pragma unroll
    for (int nt = 0; nt < FN; ++nt) bfr[0][nt] = *(const bf16x8*)(bP[nt] + kn);
#pragma unroll
    for (int mt = 0; mt < FM; ++mt)
#pragma unroll
      for (int nt = 0; nt < FN; ++nt)
        acc[mt][nt] = __builtin_amdgcn_mfma_f32_16x16x32_bf16(af[1][mt], bfr[1][nt], acc[mt][nt], 0, 0, 0);
  }

#pragma unroll
  for (int mt = 0; mt < FM; ++mt) {
#pragma unroll
    for (int nt = 0; nt < FN; ++nt) {
#pragma unroll
      for (int i = 0; i < 4; ++i) {
        int gm = m0 + wm + mt * 16 + quad * 4 + i;
        int gn = n0 + wn + nt * 16 + r;
        if (gn < N) {
          float v = acc[mt][nt][i];
          if (MODE == 0) {
            Cout[(size_t)gm * N + gn] = f2b(v);
            if (gn >= DINNER + CONVCH)
              aux[(size_t)gm * NHEADS + (gn - (DINNER + CONVCH))] = v;
          } else if (MODE == 1) {
            size_t o = (size_t)gm * N + gn;
            float hnv = aux[o] + v;
            aux[o] = hnv;
            aux2[o] = f2b(hnv);
          } else {
            aux[(size_t)gm * N + gn] = v;
          }
        }
      }
    }
  }
}

// ---------------- causal conv (K=4) + silu ----------------
__global__ void conv_k(const unsigned short* __restrict__ zx,
                       const float* __restrict__ cw,
                       const float* __restrict__ cb,
                       unsigned short* __restrict__ xbc,
                       unsigned short* __restrict__ bcb,
                       unsigned short* __restrict__ xsT) {
  int t = blockIdx.x;
  int tt = t & (T_SEQ - 1);
  int b = t >> 10;
  for (int c = threadIdx.x; c < CONVCH; c += 256) {
    float acc = cb[c];
#pragma unroll
    for (int k = 0; k < 4; ++k) {
      int tp = tt - 3 + k;
      if (tp >= 0)
        acc += b2f(zx[(size_t)(t - 3 + k) * DINPROJ + DINNER + c]) * cw[c * 4 + k];
    }
    float s = acc / (1.f + expf(-acc));
    unsigned short sb = f2b(s);
    xbc[(size_t)t * CONVCH + c] = sb;
    if (c >= DINNER) {
      bcb[(size_t)t * 256 + (c - DINNER)] = sb;
    } else {
      int hh = c >> 6, p = c & 63;
      xsT[(((size_t)b * NHEADS + hh) * HEADDIM + p) * T_SEQ + tt] = sb;
    }
  }
}

// ---------------- dt = softplus(dt_raw + bias); lnA = -dt*exp(A_log) ----------------
__global__ void dt_k(const float* __restrict__ dtraw, const float* __restrict__ dtb,
                     const float* __restrict__ alog,
                     float* __restrict__ dtf, float* __restrict__ lnAf) {
  int i = blockIdx.x * 256 + threadIdx.x;
  int h = i & (NHEADS - 1);
  float xx = dtraw[i] + dtb[h];
  float sp = (xx > 20.f) ? xx : log1pf(expf(xx));
  dtf[i] = sp;
  lnAf[i] = -sp * expf(alog[h]);
}

// ---------------- SSD pass 1: intra-chunk (per (b,h,chunk)) ----------------
__global__ __launch_bounds__(256) void ssd_intra(
    const unsigned short* __restrict__ bcb,
    const unsigned short* __restrict__ xsT,
    const float* __restrict__ dtf, const float* __restrict__ lnAf,
    unsigned short* __restrict__ y1buf, unsigned short* __restrict__ SL,
    float* __restrict__ dtot) {
  const int bi = blockIdx.x;           // ((b*32+h)*16 + c), 1024 blocks
  const int c = bi & 15;
  const int h = (bi >> 4) & 31;
  const int b = bi >> 9;
  const int tid = threadIdx.x;
  const int w = tid >> 6, l = tid & 63, r = l & 15, quad = l >> 4;
  const size_t tok0 = (size_t)b * T_SEQ + c * 64;

  __shared__ __align__(16) unsigned short BCs[64 * 264];  // [t][B0..127|C128..255]+pad
  __shared__ __align__(16) unsigned short XTs[64 * 72];   // [p][u]
  __shared__ __align__(16) unsigned short XWs[64 * 72];   // [p][u] * ws[u]
  __shared__ __align__(16) unsigned short Ms[64 * 72];    // [t][u]
  __shared__ float cumL[64], dtL[64];

#pragma unroll
  for (int i = 0; i < 8; ++i) {
    int idx = tid + i * 256;
    int row = idx >> 5, col = (idx & 31) * 8;
    uint4 v = *(const uint4*)(bcb + (tok0 + row) * 256 + col);
    *(uint4*)(BCs + row * 264 + col) = v;
  }
  const size_t xtb = ((size_t)(b * NHEADS + h) * HEADDIM) * T_SEQ + c * 64;
#pragma unroll
  for (int i = 0; i < 2; ++i) {
    int idx = tid + i * 256;
    int row = idx >> 3, col = (idx & 7) * 8;
    uint4 v = *(const uint4*)(xsT + xtb + (size_t)row * T_SEQ + col);
    *(uint4*)(XTs + row * 72 + col) = v;
  }
  if (tid < 64) {
    float v = lnAf[(tok0 + tid) * NHEADS + h];
    dtL[tid] = dtf[(tok0 + tid) * NHEADS + h];
#pragma unroll
    for (int off = 1; off < 64; off <<= 1) {
      float u = __shfl_up(v, off, 64);
      if (tid >= off) v += u;
    }
    cumL[tid] = v;
    if (tid == 63) dtot[bi] = expf(v);
  }
  __syncthreads();

  const float cum63 = cumL[63];
#pragma unroll
  for (int i = 0; i < 16; ++i) {
    int idx = tid + i * 256;
    int p = idx >> 6, u = idx & 63;
    float ws = dtL[u] * expf(cum63 - cumL[u]);
    XWs[p * 72 + u] = f2b(b2f(XTs[p * 72 + u]) * ws);
  }

  // GEMM1: G = C·B^T  (64x64, K=128)
  f32x4 g[4];
#pragma unroll
  for (int nt = 0; nt < 4; ++nt) g[nt] = f32x4{0.f, 0.f, 0.f, 0.f};
#pragma unroll
  for (int kk = 0; kk < 4; ++kk) {
    bf16x8 afr = *(const bf16x8*)(BCs + (w * 16 + r) * 264 + 128 + kk * 32 + quad * 8);
#pragma unroll
    for (int nt = 0; nt < 4; ++nt) {
      bf16x8 bfr = *(const bf16x8*)(BCs + (nt * 16 + r) * 264 + kk * 32 + quad * 8);
      g[nt] = __builtin_amdgcn_mfma_f32_16x16x32_bf16(afr, bfr, g[nt], 0, 0, 0);
    }
  }
#pragma unroll
  for (int nt = 0; nt < 4; ++nt) {
#pragma unroll
    for (int i = 0; i < 4; ++i) {
      int t_ = w * 16 + quad * 4 + i;
      int u_ = nt * 16 + r;
      float wv = (u_ <= t_) ? expf(cumL[t_] - cumL[u_]) * dtL[u_] : 0.f;
      Ms[t_ * 72 + u_] = f2b(g[nt][i] * wv);
    }
  }
  __syncthreads();

  // GEMM2: Y1 = M·X  (64t x 64p, K=64u)
  f32x4 y1[4];
#pragma unroll
  for (int nt = 0; nt < 4; ++nt) y1[nt] = f32x4{0.f, 0.f, 0.f, 0.f};
#pragma unroll
  for (int kk = 0; kk < 2; ++kk) {
    bf16x8 afr = *(const bf16x8*)(Ms + (w * 16 + r) * 72 + kk * 32 + quad * 8);
#pragma unroll
    for (int nt = 0; nt < 4; ++nt) {
      bf16x8 bfr = *(const bf16x8*)(XTs + (nt * 16 + r) * 72 + kk * 32 + quad * 8);
      y1[nt] = __builtin_amdgcn_mfma_f32_16x16x32_bf16(afr, bfr, y1[nt], 0, 0, 0);
    }
  }
#pragma unroll
  for (int nt = 0; nt < 4; ++nt)
#pragma unroll
    for (int i = 0; i < 4; ++i) {
      int t_ = w * 16 + quad * 4 + i, p_ = nt * 16 + r;
      y1buf[((size_t)bi * 64 + t_) * 64 + p_] = f2b(y1[nt][i]);
    }

  // GEMM3: Slocal = XW·B  (64p x 128n, K=64u); B-operand frag built transposed
  f32x4 sl[8];
#pragma unroll
  for (int nt = 0; nt < 8; ++nt) sl[nt] = f32x4{0.f, 0.f, 0.f, 0.f};
#pragma unroll
  for (int kk = 0; kk < 2; ++kk) {
    bf16x8 afr = *(const bf16x8*)(XWs + (w * 16 + r) * 72 + kk * 32 + quad * 8);
#pragma unroll
    for (int nt = 0; nt < 8; ++nt) {
      union { bf16x8 v; unsigned short u[8]; } bq;
#pragma unroll
      for (int j = 0; j < 8; ++j)
        bq.u[j] = BCs[(kk * 32 + quad * 8 + j) * 264 + nt * 16 + r];
      sl[nt] = __builtin_amdgcn_mfma_f32_16x16x32_bf16(afr, bq.v, sl[nt], 0, 0, 0);
    }
  }
#pragma unroll
  for (int nt = 0; nt < 8; ++nt)
#pragma unroll
    for (int i = 0; i < 4; ++i) {
      int p_ = w * 16 + quad * 4 + i, n_ = nt * 16 + r;
      SL[((size_t)bi * 64 + p_) * 128 + n_] = f2b(sl[nt][i]);
    }
}

// ---------------- SSD pass 2: chunk-state recurrence (in-place Slocal -> Spre) --------
__global__ void ssd_state(unsigned short* __restrict__ SL,
                          const float* __restrict__ dtot) {
  int gidx = blockIdx.x * 256 + threadIdx.x;   // 131072 = 64bh * 64p * 32(n/4)
  int n4 = (gidx & 31) * 4;
  int p = (gidx >> 5) & 63;
  int bh = gidx >> 11;
  float sx = 0.f, sy = 0.f, sz = 0.f, sw = 0.f;
  for (int c = 0; c < NCHUNK; ++c) {
    size_t off = ((size_t)(bh * 16 + c) * 64 + p) * 128 + n4;
    uint2 lv = *(uint2*)(SL + off);
    float d = dtot[bh * 16 + c];
    uint2 sv;
    sv.x = (unsigned)f2b(sx) | ((unsigned)f2b(sy) << 16);
    sv.y = (unsigned)f2b(sz) | ((unsigned)f2b(sw) << 16);
    *(uint2*)(SL + off) = sv;           // state BEFORE chunk c
    sx = d * sx + b2f(lv.x & 0xffff);
    sy = d * sy + b2f(lv.x >> 16);
    sz = d * sz + b2f(lv.y & 0xffff);
    sw = d * sw + b2f(lv.y >> 16);
  }
}

// ---------------- SSD pass 3: inter-chunk + combine + gate ----------------
__global__ __launch_bounds__(256) void ssd_inter(
    const unsigned short* __restrict__ bcb,
    const unsigned short* __restrict__ SL,       // holds Spre now
    const unsigned short* __restrict__ y1buf,
    const unsigned short* __restrict__ xbc,
    const unsigned short* __restrict__ zx,
    const float* __restrict__ lnAf,
    const float* __restrict__ Dw,
    unsigned short* __restrict__ yg) {
  const int bi = blockIdx.x;
  const int c = bi & 15, h = (bi >> 4) & 31, b = bi >> 9;
  const int tid = threadIdx.x;
  const int w = tid >> 6, l = tid & 63, r = l & 15, quad = l >> 4;
  const size_t tok0 = (size_t)b * T_SEQ + c * 64;

  __shared__ __align__(16) unsigned short Cs[64 * 136];
  __shared__ __align__(16) unsigned short Sp[64 * 136];
  __shared__ __align__(16) float Yf[64 * 68];
  __shared__ float cumL[64];

#pragma unroll
  for (int i = 0; i < 4; ++i) {
    int idx = tid + i * 256;
    int row = idx >> 4, col = (idx & 15) * 8;
    uint4 v = *(const uint4*)(bcb + (tok0 + row) * 256 + 128 + col);
    *(uint4*)(Cs + row * 136 + col) = v;
    uint4 s = *(const uint4*)(SL + ((size_t)bi * 64 + row) * 128 + col);
    *(uint4*)(Sp + row * 136 + col) = s;
  }
  if (tid < 64) {
    float v = lnAf[(tok0 + tid) * NHEADS + h];
#pragma unroll
    for (int off = 1; off < 64; off <<= 1) {
      float u = __shfl_up(v, off, 64);
      if (tid >= off) v += u;
    }
    cumL[tid] = v;
  }
  __syncthreads();

  // Yi[t][p] = sum_n C[t][n]*Spre[p][n]  (K=128)
  f32x4 yi[4];
#pragma unroll
  for (int nt = 0; nt < 4; ++nt) yi[nt] = f32x4{0.f, 0.f, 0.f, 0.f};
#pragma unroll
  for (int kk = 0; kk < 4; ++kk) {
    bf16x8 afr = *(const bf16x8*)(Cs + (w * 16 + r) * 136 + kk * 32 + quad * 8);
#pragma unroll
    for (int nt = 0; nt < 4; ++nt) {
      bf16x8 bfr = *(const bf16x8*)(Sp + (nt * 16 + r) * 136 + kk * 32 + quad * 8);
      yi[nt] = __builtin_amdgcn_mfma_f32_16x16x32_bf16(afr, bfr, yi[nt], 0, 0, 0);
    }
  }
#pragma unroll
  for (int nt = 0; nt < 4; ++nt)
#pragma unroll
    for (int i = 0; i < 4; ++i) {
      int t_ = w * 16 + quad * 4 + i, p_ = nt * 16 + r;
      float y1 = b2f(y1buf[((size_t)bi * 64 + t_) * 64 + p_]);
      Yf[t_ * 68 + p_] = y1 + expf(cumL[t_]) * yi[nt][i];
    }
  __syncthreads();

  // combine: y = Yf + D*x, gate with silu(z), write yg
  const float Dh = Dw[h];
  const int t_ = tid >> 2, pg = (tid & 3) * 16;
  const size_t tok = tok0 + t_;
  union { uint4 q[2]; unsigned short u[16]; } xv, zv, ov;
  xv.q[0] = *(const uint4*)(xbc + tok * CONVCH + h * 64 + pg);
  xv.q[1] = *(const uint4*)(xbc + tok * CONVCH + h * 64 + pg + 8);
  zv.q[0] = *(const uint4*)(zx + tok * DINPROJ + h * 64 + pg);
  zv.q[1] = *(const uint4*)(zx + tok * DINPROJ + h * 64 + pg + 8);
#pragma unroll
  for (int j = 0; j < 16; ++j) {
    float y = Yf[t_ * 68 + pg + j] + Dh * b2f(xv.u[j]);
    float zf = b2f(zv.u[j]);
    ov.u[j] = f2b(y * (zf / (1.f + expf(-zf))));
  }
  *(uint4*)(yg + tok * DINNER + h * 64 + pg) = ov.q[0];
  *(uint4*)(yg + tok * DINNER + h * 64 + pg + 8) = ov.q[1];
}

// ---------------- RMSNorm over 2048 ----------------
__global__ void rms2048_k(const unsigned short* __restrict__ in,
                          const float* __restrict__ w,
                          unsigned short* __restrict__ out) {
  int t = blockIdx.x;
  int base = threadIdx.x * 8;
  union { uint4 q; unsigned short u[8]; } vv;
  vv.q = *(const uint4*)(in + (size_t)t * DINNER + base);
  float f[8];
  float ss = 0.f;
#pragma unroll
  for (int j = 0; j < 8; ++j) { f[j] = b2f(vv.u[j]); ss += f[j] * f[j]; }
#pragma unroll
  for (int o = 32; o > 0; o >>= 1) ss += __shfl_xor(ss, o, 64);
  __shared__ float red[4];
  if ((threadIdx.x & 63) == 0) red[threadIdx.x >> 6] = ss;
  __syncthreads();
  ss = red[0] + red[1] + red[2] + red[3];
  float scale = rsqrtf(ss * (1.f / DINNER) + EPS_F);
#pragma unroll
  for (int j = 0; j < 8; ++j)
    out[(size_t)t * DINNER + base + j] = f2b(f[j] * scale * w[base + j]);
}

// ---------------- final RMSNorm over 1024 ----------------
__global__ void rmsfinal_k(const float* __restrict__ hf,
                           const float* __restrict__ w,
                           unsigned short* __restrict__ out) {
  int t = blockIdx.x;
  int base = threadIdx.x * 4;
  float4 v = *(const float4*)(hf + (size_t)t * DIM + base);
  float ss = v.x * v.x + v.y * v.y + v.z * v.z + v.w * v.w;
#pragma unroll
  for (int o = 32; o > 0; o >>= 1) ss += __shfl_xor(ss, o, 64);
  __shared__ float red[4];
  if ((threadIdx.x & 63) == 0) red[threadIdx.x >> 6] = ss;
  __syncthreads();
  ss = red[0] + red[1] + red[2] + red[3];
  float scale = rsqrtf(ss * (1.f / DIM) + EPS_F);
  out[(size_t)t * DIM + base + 0] = f2b(v.x * scale * w[base + 0]);
  out[(size_t)t * DIM + base + 1] = f2b(v.y * scale * w[base + 1]);
  out[(size_t)t * DIM + base + 2] = f2b(v.z * scale * w[base + 2]);
  out[(size_t)t * DIM + base + 3] = f2b(v.w * scale * w[base + 3]);
}

extern "C" void kernel_launch(void* const* d_in, const int* in_sizes, int n_in,
                              void* d_out, int out_size, void* d_ws, size_t ws_size,
                              hipStream_t stream) {
  const int*   x    = (const int*)d_in[0];
  const float* emb  = (const float*)d_in[1];
  const float* Wp   = (const float*)d_in[2];
  const float* cw   = (const float*)d_in[3];
  const float* cb   = (const float*)d_in[4];
  const float* dtb  = (const float*)d_in[5];
  const float* alog = (const float*)d_in[6];
  const float* Dw   = (const float*)d_in[7];
  const float* gw   = (const float*)d_in[8];
  const float* Wo   = (const float*)d_in[9];
  const float* fnw  = (const float*)d_in[10];

  char* w = (char*)d_ws;
  auto alloc = [&](size_t bytes) {
    char* p = w; w += (bytes + 255) & ~(size_t)255; return p;
  };
  float* h_f32          = (float*)alloc((size_t)BT * DIM * 4);
  unsigned short* hb    = (unsigned short*)alloc((size_t)BT * DIM * 2);
  unsigned short* zx    = (unsigned short*)alloc((size_t)BT * DINPROJ * 2);
  float* dtraw          = (float*)alloc((size_t)BT * NHEADS * 4);
  float* dtf            = (float*)alloc((size_t)BT * NHEADS * 4);
  float* lnAf           = (float*)alloc((size_t)BT * NHEADS * 4);
  unsigned short* xbc   = (unsigned short*)alloc((size_t)BT * CONVCH * 2);
  unsigned short* bcb   = (unsigned short*)alloc((size_t)BT * 256 * 2);
  unsigned short* xsT   = (unsigned short*)alloc((size_t)BT * DINNER * 2);
  unsigned short* SL    = (unsigned short*)alloc((size_t)1024 * 64 * 128 * 2);
  unsigned short* y1buf = (unsigned short*)alloc((size_t)1024 * 64 * 64 * 2);
  float* dtot           = (float*)alloc((size_t)1024 * 4);
  unsigned short* yg    = (unsigned short*)alloc((size_t)BT * DINNER * 2);
  unsigned short* yn    = (unsigned short*)alloc((size_t)BT * DINNER * 2);
  unsigned short* hn    = (unsigned short*)alloc((size_t)BT * DIM * 2);
  unsigned short* Wp_b  = (unsigned short*)alloc((size_t)2 * DINPROJ * DIM * 2);
  unsigned short* Wo_b  = (unsigned short*)alloc((size_t)2 * DIM * DINNER * 2);
  unsigned short* emb_b = (unsigned short*)alloc((size_t)256 * DIM * 2 + 256);

  {
    int nWp = 2 * DINPROJ * DIM;
    int nWo = 2 * DIM * DINNER;
    int nEm = 256 * DIM;
    cvt_k<<<(nWp / 4 + 255) / 256, 256, 0, stream>>>(Wp, Wp_b, nWp);
    cvt_k<<<(nWo / 4 + 255) / 256, 256, 0, stream>>>(Wo, Wo_b, nWo);
    cvt_k<<<(nEm / 4 + 255) / 256, 256, 0, stream>>>(emb, emb_b, nEm);
  }

  embed_k<<<BT, 256, 0, stream>>>(x, emb, h_f32, hb);

  for (int l = 0; l < 2; ++l) {
    const unsigned short* Wpl = Wp_b + (size_t)l * DINPROJ * DIM;
    const unsigned short* Wol = Wo_b + (size_t)l * DIM * DINNER;
    const float* cwl   = cw + (size_t)l * CONVCH * 4;
    const float* cbl   = cb + (size_t)l * CONVCH;
    const float* dtbl  = dtb + l * NHEADS;
    const float* alogl = alog + l * NHEADS;
    const float* Dwl   = Dw + l * NHEADS;
    const float* gwl   = gw + (size_t)l * DINNER;

    gemm_flat<0, 128, 128><<<dim3(35, 16), 256, 0, stream>>>(hb, Wpl, BT, DINPROJ, DIM, zx, dtraw, nullptr);
    conv_k<<<BT, 256, 0, stream>>>(zx, cwl, cbl, xbc, bcb, xsT);
    dt_k<<<BT * NHEADS / 256, 256, 0, stream>>>(dtraw, dtbl, alogl, dtf, lnAf);
    ssd_intra<<<1024, 256, 0, stream>>>(bcb, xsT, dtf, lnAf, y1buf, SL, dtot);
    ssd_state<<<512, 256, 0, stream>>>(SL, dtot);
    ssd_inter<<<1024, 256, 0, stream>>>(bcb, SL, y1buf, xbc, zx, lnAf, Dwl, yg);
    rms2048_k<<<BT, 256, 0, stream>>>(yg, gwl, yn);
    gemm_flat<1, 64, 64><<<dim3(16, 32), 256, 0, stream>>>(yn, Wol, BT, DIM, DINNER, nullptr, h_f32, hb);
  }

  rmsfinal_k<<<BT, 256, 0, stream>>>(h_f32, fnw, hn);
  gemm_flat<2, 64, 64><<<dim3(4, 32), 256, 0, stream>>>(hn, emb_b, BT, 256, DIM,
                                                        nullptr, (float*)d_out, nullptr);
}

// Round 8
// 515.721 us; speedup vs baseline: 1.2959x; 1.2959x over previous
//
#include <hip/hip_runtime.h>
#include <hip/hip_bf16.h>

#define BT 2048
#define T_SEQ 1024
#define DIM 1024
#define DINNER 2048
#define DSTATE 128
#define HEADDIM 64
#define NHEADS 32
#define CONVCH 2304
#define DINPROJ 4384
#define EPS_F 1e-5f
#define NCHUNK 16   // T_SEQ / 64

typedef __bf16 bf16x8 __attribute__((ext_vector_type(8)));
typedef float f32x4 __attribute__((ext_vector_type(4)));

__device__ __forceinline__ float b2f(unsigned short u) {
  union { unsigned int i; float f; } v; v.i = ((unsigned int)u) << 16; return v.f;
}
__device__ __forceinline__ unsigned short f2b(float f) {
  unsigned int x = __float_as_uint(f);
  return (unsigned short)((x + 0x7fffu + ((x >> 16) & 1u)) >> 16);
}

// async global->LDS DMA: per-lane global addr, LDS dest = wave-uniform base + lane*16
__device__ __forceinline__ void gload_lds16(const void* g, void* l) {
  __builtin_amdgcn_global_load_lds(
      (const __attribute__((address_space(1))) unsigned int*)g,
      (__attribute__((address_space(3))) unsigned int*)l, 16, 0, 0);
}

// ---------------- fp32 -> bf16 weight conversion ----------------
__global__ void cvt_k(const float* __restrict__ in, unsigned short* __restrict__ out, int n) {
  int i = (blockIdx.x * 256 + threadIdx.x) * 4;
  if (i < n) {
    float4 v = *(const float4*)(in + i);
    out[i + 0] = f2b(v.x);
    out[i + 1] = f2b(v.y);
    out[i + 2] = f2b(v.z);
    out[i + 3] = f2b(v.w);
  }
}

// ---------------- embed lookup ----------------
__global__ void embed_k(const int* __restrict__ x, const float* __restrict__ emb,
                        float* __restrict__ h, unsigned short* __restrict__ hb) {
  int t = blockIdx.x;
  int tok = x[t];
  int d = threadIdx.x;
#pragma unroll
  for (int j = 0; j < 4; ++j, d += 256) {
    float v = emb[(size_t)tok * DIM + d];
    h[(size_t)t * DIM + d] = v;
    hb[(size_t)t * DIM + d] = f2b(v);
  }
}

// ---------------- PER-WAVE GEMM: C[M,N] = A[M,K] * Bw[N,K]^T (bf16, fp32 acc) ---------
// 64x64 block tile, 4 waves (2x2), each wave owns a 32x32 quadrant and stages ONLY the
// 32 A-rows + 32 B-rows it reads into its private 8KB LDS region. ZERO __syncthreads:
// no block-wide vmcnt(0) convoy (round-6's structural stall). Double-buffered BK=32
// stages; manual s_waitcnt vmcnt(4) keeps next stage's DMAs in flight. 20 waves/CU
// slip independently -> latency hidden by TLP.
template <int MODE>
__global__ __launch_bounds__(256) void gemm_pw(
    const unsigned short* __restrict__ A,
    const unsigned short* __restrict__ Bw,
    int M, int N, int K,
    unsigned short* __restrict__ Cout,
    float* __restrict__ aux,
    unsigned short* __restrict__ aux2) {
  __shared__ __align__(16) unsigned short lds[4 * 4096];  // 32KB: 8KB/wave
  const int tid = threadIdx.x;
  const int lane = tid & 63;
  const int wave = tid >> 6;
  const int m0 = blockIdx.y * 64;
  const int n0 = blockIdx.x * 64;
  const int wm = (wave >> 1) * 32;
  const int wn = (wave & 1) * 32;
  const int quad = lane >> 4;
  const int r = lane & 15;

  unsigned short* base = lds + wave * 4096;  // shorts; layout: A0|A1|B0|B1, 1024 sh each

  // staging source pointers: lane -> (row = lane>>2, 16B chunk = (lane&3)*8 shorts)
  const int arow = m0 + wm + (lane >> 2);
  const unsigned short* aG0 = A + (size_t)arow * K + (lane & 3) * 8;
  const unsigned short* aG1 = aG0 + (size_t)16 * K;
  int brow0 = n0 + wn + (lane >> 2); if (brow0 > N - 1) brow0 = N - 1;
  int brow1 = brow0 + 16;            if (brow1 > N - 1) brow1 = N - 1;
  const unsigned short* bG0 = Bw + (size_t)brow0 * K + (lane & 3) * 8;
  const unsigned short* bG1 = Bw + (size_t)brow1 * K + (lane & 3) * 8;

#define PW_STAGE(ks, buf)                                   \
  {                                                         \
    gload_lds16(aG0 + (ks), base + (buf) * 1024);           \
    gload_lds16(aG1 + (ks), base + (buf) * 1024 + 512);     \
    gload_lds16(bG0 + (ks), base + 2048 + (buf) * 1024);    \
    gload_lds16(bG1 + (ks), base + 2048 + (buf) * 1024 + 512); \
  }

  f32x4 acc00 = f32x4{0.f, 0.f, 0.f, 0.f}, acc01 = acc00, acc10 = acc00, acc11 = acc00;

  const int NK = K >> 5;  // K/32, >= 32 for all our shapes
  PW_STAGE(0, 0);
  PW_STAGE(32, 1);

  const int foff = r * 32 + quad * 8;  // frag offset within a 1KB half: row*64B + quad*16B
  for (int k0 = 0; k0 < NK; ++k0) {
    const int cur = k0 & 1;
    // wait for THIS wave's stage k0 (4 DMAs); stage k0+1's 4 stay in flight
    if (k0 + 1 < NK) __builtin_amdgcn_s_waitcnt(0x0F74);  // vmcnt(4)
    else             __builtin_amdgcn_s_waitcnt(0x0F70);  // vmcnt(0)
    __builtin_amdgcn_sched_barrier(0);
    bf16x8 a0 = *(const bf16x8*)(base + cur * 1024 + foff);
    bf16x8 a1 = *(const bf16x8*)(base + cur * 1024 + 512 + foff);
    bf16x8 b0 = *(const bf16x8*)(base + 2048 + cur * 1024 + foff);
    bf16x8 b1 = *(const bf16x8*)(base + 2048 + cur * 1024 + 512 + foff);
    acc00 = __builtin_amdgcn_mfma_f32_16x16x32_bf16(a0, b0, acc00, 0, 0, 0);
    acc01 = __builtin_amdgcn_mfma_f32_16x16x32_bf16(a0, b1, acc01, 0, 0, 0);
    acc10 = __builtin_amdgcn_mfma_f32_16x16x32_bf16(a1, b0, acc10, 0, 0, 0);
    acc11 = __builtin_amdgcn_mfma_f32_16x16x32_bf16(a1, b1, acc11, 0, 0, 0);
    if (k0 + 2 < NK) {
      // ds_reads above must land before DMA overwrites cur buf (different pipes!)
      __builtin_amdgcn_s_waitcnt(0xC07F);  // lgkmcnt(0) only
      __builtin_amdgcn_sched_barrier(0);
      PW_STAGE((k0 + 2) * 32, cur);
    }
  }
#undef PW_STAGE

  const f32x4* accp[2][2] = {{&acc00, &acc01}, {&acc10, &acc11}};
#pragma unroll
  for (int mt = 0; mt < 2; ++mt) {
#pragma unroll
    for (int nt = 0; nt < 2; ++nt) {
#pragma unroll
      for (int i = 0; i < 4; ++i) {
        int gm = m0 + wm + mt * 16 + quad * 4 + i;
        int gn = n0 + wn + nt * 16 + r;
        if (gn < N) {
          float v = (*accp[mt][nt])[i];
          if (MODE == 0) {
            Cout[(size_t)gm * N + gn] = f2b(v);
            if (gn >= DINNER + CONVCH)
              aux[(size_t)gm * NHEADS + (gn - (DINNER + CONVCH))] = v;
          } else if (MODE == 1) {
            size_t o = (size_t)gm * N + gn;
            float hnv = aux[o] + v;
            aux[o] = hnv;
            aux2[o] = f2b(hnv);
          } else {
            aux[(size_t)gm * N + gn] = v;
          }
        }
      }
    }
  }
}

// ---------------- causal conv (K=4) + silu ----------------
__global__ void conv_k(const unsigned short* __restrict__ zx,
                       const float* __restrict__ cw,
                       const float* __restrict__ cb,
                       unsigned short* __restrict__ xbc,
                       unsigned short* __restrict__ bcb,
                       unsigned short* __restrict__ xsT) {
  int t = blockIdx.x;
  int tt = t & (T_SEQ - 1);
  int b = t >> 10;
  for (int c = threadIdx.x; c < CONVCH; c += 256) {
    float acc = cb[c];
#pragma unroll
    for (int k = 0; k < 4; ++k) {
      int tp = tt - 3 + k;
      if (tp >= 0)
        acc += b2f(zx[(size_t)(t - 3 + k) * DINPROJ + DINNER + c]) * cw[c * 4 + k];
    }
    float s = acc / (1.f + expf(-acc));
    unsigned short sb = f2b(s);
    xbc[(size_t)t * CONVCH + c] = sb;
    if (c >= DINNER) {
      bcb[(size_t)t * 256 + (c - DINNER)] = sb;
    } else {
      int hh = c >> 6, p = c & 63;
      xsT[(((size_t)b * NHEADS + hh) * HEADDIM + p) * T_SEQ + tt] = sb;
    }
  }
}

// ---------------- dt = softplus(dt_raw + bias); lnA = -dt*exp(A_log) ----------------
__global__ void dt_k(const float* __restrict__ dtraw, const float* __restrict__ dtb,
                     const float* __restrict__ alog,
                     float* __restrict__ dtf, float* __restrict__ lnAf) {
  int i = blockIdx.x * 256 + threadIdx.x;
  int h = i & (NHEADS - 1);
  float xx = dtraw[i] + dtb[h];
  float sp = (xx > 20.f) ? xx : log1pf(expf(xx));
  dtf[i] = sp;
  lnAf[i] = -sp * expf(alog[h]);
}

// ---------------- SSD pass 1: intra-chunk (per (b,h,chunk)) ----------------
__global__ __launch_bounds__(256) void ssd_intra(
    const unsigned short* __restrict__ bcb,
    const unsigned short* __restrict__ xsT,
    const float* __restrict__ dtf, const float* __restrict__ lnAf,
    unsigned short* __restrict__ y1buf, unsigned short* __restrict__ SL,
    float* __restrict__ dtot) {
  const int bi = blockIdx.x;           // ((b*32+h)*16 + c), 1024 blocks
  const int c = bi & 15;
  const int h = (bi >> 4) & 31;
  const int b = bi >> 9;
  const int tid = threadIdx.x;
  const int w = tid >> 6, l = tid & 63, r = l & 15, quad = l >> 4;
  const size_t tok0 = (size_t)b * T_SEQ + c * 64;

  __shared__ __align__(16) unsigned short BCs[64 * 264];  // [t][B0..127|C128..255]+pad
  __shared__ __align__(16) unsigned short XTs[64 * 72];   // [p][u]
  __shared__ __align__(16) unsigned short XWs[64 * 72];   // [p][u] * ws[u]
  __shared__ __align__(16) unsigned short Ms[64 * 72];    // [t][u]
  __shared__ float cumL[64], dtL[64];

#pragma unroll
  for (int i = 0; i < 8; ++i) {
    int idx = tid + i * 256;
    int row = idx >> 5, col = (idx & 31) * 8;
    uint4 v = *(const uint4*)(bcb + (tok0 + row) * 256 + col);
    *(uint4*)(BCs + row * 264 + col) = v;
  }
  const size_t xtb = ((size_t)(b * NHEADS + h) * HEADDIM) * T_SEQ + c * 64;
#pragma unroll
  for (int i = 0; i < 2; ++i) {
    int idx = tid + i * 256;
    int row = idx >> 3, col = (idx & 7) * 8;
    uint4 v = *(const uint4*)(xsT + xtb + (size_t)row * T_SEQ + col);
    *(uint4*)(XTs + row * 72 + col) = v;
  }
  if (tid < 64) {
    float v = lnAf[(tok0 + tid) * NHEADS + h];
    dtL[tid] = dtf[(tok0 + tid) * NHEADS + h];
#pragma unroll
    for (int off = 1; off < 64; off <<= 1) {
      float u = __shfl_up(v, off, 64);
      if (tid >= off) v += u;
    }
    cumL[tid] = v;
    if (tid == 63) dtot[bi] = expf(v);
  }
  __syncthreads();

  const float cum63 = cumL[63];
#pragma unroll
  for (int i = 0; i < 16; ++i) {
    int idx = tid + i * 256;
    int p = idx >> 6, u = idx & 63;
    float ws = dtL[u] * expf(cum63 - cumL[u]);
    XWs[p * 72 + u] = f2b(b2f(XTs[p * 72 + u]) * ws);
  }

  // GEMM1: G = C·B^T  (64x64, K=128)
  f32x4 g[4];
#pragma unroll
  for (int nt = 0; nt < 4; ++nt) g[nt] = f32x4{0.f, 0.f, 0.f, 0.f};
#pragma unroll
  for (int kk = 0; kk < 4; ++kk) {
    bf16x8 afr = *(const bf16x8*)(BCs + (w * 16 + r) * 264 + 128 + kk * 32 + quad * 8);
#pragma unroll
    for (int nt = 0; nt < 4; ++nt) {
      bf16x8 bfr = *(const bf16x8*)(BCs + (nt * 16 + r) * 264 + kk * 32 + quad * 8);
      g[nt] = __builtin_amdgcn_mfma_f32_16x16x32_bf16(afr, bfr, g[nt], 0, 0, 0);
    }
  }
#pragma unroll
  for (int nt = 0; nt < 4; ++nt) {
#pragma unroll
    for (int i = 0; i < 4; ++i) {
      int t_ = w * 16 + quad * 4 + i;
      int u_ = nt * 16 + r;
      float wv = (u_ <= t_) ? expf(cumL[t_] - cumL[u_]) * dtL[u_] : 0.f;
      Ms[t_ * 72 + u_] = f2b(g[nt][i] * wv);
    }
  }
  __syncthreads();

  // GEMM2: Y1 = M·X  (64t x 64p, K=64u)
  f32x4 y1[4];
#pragma unroll
  for (int nt = 0; nt < 4; ++nt) y1[nt] = f32x4{0.f, 0.f, 0.f, 0.f};
#pragma unroll
  for (int kk = 0; kk < 2; ++kk) {
    bf16x8 afr = *(const bf16x8*)(Ms + (w * 16 + r) * 72 + kk * 32 + quad * 8);
#pragma unroll
    for (int nt = 0; nt < 4; ++nt) {
      bf16x8 bfr = *(const bf16x8*)(XTs + (nt * 16 + r) * 72 + kk * 32 + quad * 8);
      y1[nt] = __builtin_amdgcn_mfma_f32_16x16x32_bf16(afr, bfr, y1[nt], 0, 0, 0);
    }
  }
#pragma unroll
  for (int nt = 0; nt < 4; ++nt)
#pragma unroll
    for (int i = 0; i < 4; ++i) {
      int t_ = w * 16 + quad * 4 + i, p_ = nt * 16 + r;
      y1buf[((size_t)bi * 64 + t_) * 64 + p_] = f2b(y1[nt][i]);
    }

  // GEMM3: Slocal = XW·B  (64p x 128n, K=64u); B-operand frag built transposed
  f32x4 sl[8];
#pragma unroll
  for (int nt = 0; nt < 8; ++nt) sl[nt] = f32x4{0.f, 0.f, 0.f, 0.f};
#pragma unroll
  for (int kk = 0; kk < 2; ++kk) {
    bf16x8 afr = *(const bf16x8*)(XWs + (w * 16 + r) * 72 + kk * 32 + quad * 8);
#pragma unroll
    for (int nt = 0; nt < 8; ++nt) {
      union { bf16x8 v; unsigned short u[8]; } bq;
#pragma unroll
      for (int j = 0; j < 8; ++j)
        bq.u[j] = BCs[(kk * 32 + quad * 8 + j) * 264 + nt * 16 + r];
      sl[nt] = __builtin_amdgcn_mfma_f32_16x16x32_bf16(afr, bq.v, sl[nt], 0, 0, 0);
    }
  }
#pragma unroll
  for (int nt = 0; nt < 8; ++nt)
#pragma unroll
    for (int i = 0; i < 4; ++i) {
      int p_ = w * 16 + quad * 4 + i, n_ = nt * 16 + r;
      SL[((size_t)bi * 64 + p_) * 128 + n_] = f2b(sl[nt][i]);
    }
}

// ---------------- SSD pass 2: chunk-state recurrence (in-place Slocal -> Spre) --------
__global__ void ssd_state(unsigned short* __restrict__ SL,
                          const float* __restrict__ dtot) {
  int gidx = blockIdx.x * 256 + threadIdx.x;   // 131072 = 64bh * 64p * 32(n/4)
  int n4 = (gidx & 31) * 4;
  int p = (gidx >> 5) & 63;
  int bh = gidx >> 11;
  float sx = 0.f, sy = 0.f, sz = 0.f, sw = 0.f;
  for (int c = 0; c < NCHUNK; ++c) {
    size_t off = ((size_t)(bh * 16 + c) * 64 + p) * 128 + n4;
    uint2 lv = *(uint2*)(SL + off);
    float d = dtot[bh * 16 + c];
    uint2 sv;
    sv.x = (unsigned)f2b(sx) | ((unsigned)f2b(sy) << 16);
    sv.y = (unsigned)f2b(sz) | ((unsigned)f2b(sw) << 16);
    *(uint2*)(SL + off) = sv;           // state BEFORE chunk c
    sx = d * sx + b2f(lv.x & 0xffff);
    sy = d * sy + b2f(lv.x >> 16);
    sz = d * sz + b2f(lv.y & 0xffff);
    sw = d * sw + b2f(lv.y >> 16);
  }
}

// ---------------- SSD pass 3: inter-chunk + combine + gate ----------------
__global__ __launch_bounds__(256) void ssd_inter(
    const unsigned short* __restrict__ bcb,
    const unsigned short* __restrict__ SL,       // holds Spre now
    const unsigned short* __restrict__ y1buf,
    const unsigned short* __restrict__ xbc,
    const unsigned short* __restrict__ zx,
    const float* __restrict__ lnAf,
    const float* __restrict__ Dw,
    unsigned short* __restrict__ yg) {
  const int bi = blockIdx.x;
  const int c = bi & 15, h = (bi >> 4) & 31, b = bi >> 9;
  const int tid = threadIdx.x;
  const int w = tid >> 6, l = tid & 63, r = l & 15, quad = l >> 4;
  const size_t tok0 = (size_t)b * T_SEQ + c * 64;

  __shared__ __align__(16) unsigned short Cs[64 * 136];
  __shared__ __align__(16) unsigned short Sp[64 * 136];
  __shared__ __align__(16) float Yf[64 * 68];
  __shared__ float cumL[64];

#pragma unroll
  for (int i = 0; i < 4; ++i) {
    int idx = tid + i * 256;
    int row = idx >> 4, col = (idx & 15) * 8;
    uint4 v = *(const uint4*)(bcb + (tok0 + row) * 256 + 128 + col);
    *(uint4*)(Cs + row * 136 + col) = v;
    uint4 s = *(const uint4*)(SL + ((size_t)bi * 64 + row) * 128 + col);
    *(uint4*)(Sp + row * 136 + col) = s;
  }
  if (tid < 64) {
    float v = lnAf[(tok0 + tid) * NHEADS + h];
#pragma unroll
    for (int off = 1; off < 64; off <<= 1) {
      float u = __shfl_up(v, off, 64);
      if (tid >= off) v += u;
    }
    cumL[tid] = v;
  }
  __syncthreads();

  // Yi[t][p] = sum_n C[t][n]*Spre[p][n]  (K=128)
  f32x4 yi[4];
#pragma unroll
  for (int nt = 0; nt < 4; ++nt) yi[nt] = f32x4{0.f, 0.f, 0.f, 0.f};
#pragma unroll
  for (int kk = 0; kk < 4; ++kk) {
    bf16x8 afr = *(const bf16x8*)(Cs + (w * 16 + r) * 136 + kk * 32 + quad * 8);
#pragma unroll
    for (int nt = 0; nt < 4; ++nt) {
      bf16x8 bfr = *(const bf16x8*)(Sp + (nt * 16 + r) * 136 + kk * 32 + quad * 8);
      yi[nt] = __builtin_amdgcn_mfma_f32_16x16x32_bf16(afr, bfr, yi[nt], 0, 0, 0);
    }
  }
#pragma unroll
  for (int nt = 0; nt < 4; ++nt)
#pragma unroll
    for (int i = 0; i < 4; ++i) {
      int t_ = w * 16 + quad * 4 + i, p_ = nt * 16 + r;
      float y1 = b2f(y1buf[((size_t)bi * 64 + t_) * 64 + p_]);
      Yf[t_ * 68 + p_] = y1 + expf(cumL[t_]) * yi[nt][i];
    }
  __syncthreads();

  // combine: y = Yf + D*x, gate with silu(z), write yg
  const float Dh = Dw[h];
  const int t_ = tid >> 2, pg = (tid & 3) * 16;
  const size_t tok = tok0 + t_;
  union { uint4 q[2]; unsigned short u[16]; } xv, zv, ov;
  xv.q[0] = *(const uint4*)(xbc + tok * CONVCH + h * 64 + pg);
  xv.q[1] = *(const uint4*)(xbc + tok * CONVCH + h * 64 + pg + 8);
  zv.q[0] = *(const uint4*)(zx + tok * DINPROJ + h * 64 + pg);
  zv.q[1] = *(const uint4*)(zx + tok * DINPROJ + h * 64 + pg + 8);
#pragma unroll
  for (int j = 0; j < 16; ++j) {
    float y = Yf[t_ * 68 + pg + j] + Dh * b2f(xv.u[j]);
    float zf = b2f(zv.u[j]);
    ov.u[j] = f2b(y * (zf / (1.f + expf(-zf))));
  }
  *(uint4*)(yg + tok * DINNER + h * 64 + pg) = ov.q[0];
  *(uint4*)(yg + tok * DINNER + h * 64 + pg + 8) = ov.q[1];
}

// ---------------- RMSNorm over 2048 ----------------
__global__ void rms2048_k(const unsigned short* __restrict__ in,
                          const float* __restrict__ w,
                          unsigned short* __restrict__ out) {
  int t = blockIdx.x;
  int base = threadIdx.x * 8;
  union { uint4 q; unsigned short u[8]; } vv;
  vv.q = *(const uint4*)(in + (size_t)t * DINNER + base);
  float f[8];
  float ss = 0.f;
#pragma unroll
  for (int j = 0; j < 8; ++j) { f[j] = b2f(vv.u[j]); ss += f[j] * f[j]; }
#pragma unroll
  for (int o = 32; o > 0; o >>= 1) ss += __shfl_xor(ss, o, 64);
  __shared__ float red[4];
  if ((threadIdx.x & 63) == 0) red[threadIdx.x >> 6] = ss;
  __syncthreads();
  ss = red[0] + red[1] + red[2] + red[3];
  float scale = rsqrtf(ss * (1.f / DINNER) + EPS_F);
#pragma unroll
  for (int j = 0; j < 8; ++j)
    out[(size_t)t * DINNER + base + j] = f2b(f[j] * scale * w[base + j]);
}

// ---------------- final RMSNorm over 1024 ----------------
__global__ void rmsfinal_k(const float* __restrict__ hf,
                           const float* __restrict__ w,
                           unsigned short* __restrict__ out) {
  int t = blockIdx.x;
  int base = threadIdx.x * 4;
  float4 v = *(const float4*)(hf + (size_t)t * DIM + base);
  float ss = v.x * v.x + v.y * v.y + v.z * v.z + v.w * v.w;
#pragma unroll
  for (int o = 32; o > 0; o >>= 1) ss += __shfl_xor(ss, o, 64);
  __shared__ float red[4];
  if ((threadIdx.x & 63) == 0) red[threadIdx.x >> 6] = ss;
  __syncthreads();
  ss = red[0] + red[1] + red[2] + red[3];
  float scale = rsqrtf(ss * (1.f / DIM) + EPS_F);
  out[(size_t)t * DIM + base + 0] = f2b(v.x * scale * w[base + 0]);
  out[(size_t)t * DIM + base + 1] = f2b(v.y * scale * w[base + 1]);
  out[(size_t)t * DIM + base + 2] = f2b(v.z * scale * w[base + 2]);
  out[(size_t)t * DIM + base + 3] = f2b(v.w * scale * w[base + 3]);
}

extern "C" void kernel_launch(void* const* d_in, const int* in_sizes, int n_in,
                              void* d_out, int out_size, void* d_ws, size_t ws_size,
                              hipStream_t stream) {
  const int*   x    = (const int*)d_in[0];
  const float* emb  = (const float*)d_in[1];
  const float* Wp   = (const float*)d_in[2];
  const float* cw   = (const float*)d_in[3];
  const float* cb   = (const float*)d_in[4];
  const float* dtb  = (const float*)d_in[5];
  const float* alog = (const float*)d_in[6];
  const float* Dw   = (const float*)d_in[7];
  const float* gw   = (const float*)d_in[8];
  const float* Wo   = (const float*)d_in[9];
  const float* fnw  = (const float*)d_in[10];

  char* w = (char*)d_ws;
  auto alloc = [&](size_t bytes) {
    char* p = w; w += (bytes + 255) & ~(size_t)255; return p;
  };
  float* h_f32          = (float*)alloc((size_t)BT * DIM * 4);
  unsigned short* hb    = (unsigned short*)alloc((size_t)BT * DIM * 2);
  unsigned short* zx    = (unsigned short*)alloc((size_t)BT * DINPROJ * 2);
  float* dtraw          = (float*)alloc((size_t)BT * NHEADS * 4);
  float* dtf            = (float*)alloc((size_t)BT * NHEADS * 4);
  float* lnAf           = (float*)alloc((size_t)BT * NHEADS * 4);
  unsigned short* xbc   = (unsigned short*)alloc((size_t)BT * CONVCH * 2);
  unsigned short* bcb   = (unsigned short*)alloc((size_t)BT * 256 * 2);
  unsigned short* xsT   = (unsigned short*)alloc((size_t)BT * DINNER * 2);
  unsigned short* SL    = (unsigned short*)alloc((size_t)1024 * 64 * 128 * 2);
  unsigned short* y1buf = (unsigned short*)alloc((size_t)1024 * 64 * 64 * 2);
  float* dtot           = (float*)alloc((size_t)1024 * 4);
  unsigned short* yg    = (unsigned short*)alloc((size_t)BT * DINNER * 2);
  unsigned short* yn    = (unsigned short*)alloc((size_t)BT * DINNER * 2);
  unsigned short* hn    = (unsigned short*)alloc((size_t)BT * DIM * 2);
  unsigned short* Wp_b  = (unsigned short*)alloc((size_t)2 * DINPROJ * DIM * 2);
  unsigned short* Wo_b  = (unsigned short*)alloc((size_t)2 * DIM * DINNER * 2);
  unsigned short* emb_b = (unsigned short*)alloc((size_t)256 * DIM * 2 + 256);

  {
    int nWp = 2 * DINPROJ * DIM;
    int nWo = 2 * DIM * DINNER;
    int nEm = 256 * DIM;
    cvt_k<<<(nWp / 4 + 255) / 256, 256, 0, stream>>>(Wp, Wp_b, nWp);
    cvt_k<<<(nWo / 4 + 255) / 256, 256, 0, stream>>>(Wo, Wo_b, nWo);
    cvt_k<<<(nEm / 4 + 255) / 256, 256, 0, stream>>>(emb, emb_b, nEm);
  }

  embed_k<<<BT, 256, 0, stream>>>(x, emb, h_f32, hb);

  for (int l = 0; l < 2; ++l) {
    const unsigned short* Wpl = Wp_b + (size_t)l * DINPROJ * DIM;
    const unsigned short* Wol = Wo_b + (size_t)l * DIM * DINNER;
    const float* cwl   = cw + (size_t)l * CONVCH * 4;
    const float* cbl   = cb + (size_t)l * CONVCH;
    const float* dtbl  = dtb + l * NHEADS;
    const float* alogl = alog + l * NHEADS;
    const float* Dwl   = Dw + l * NHEADS;
    const float* gwl   = gw + (size_t)l * DINNER;

    gemm_pw<0><<<dim3(69, 32), 256, 0, stream>>>(hb, Wpl, BT, DINPROJ, DIM, zx, dtraw, nullptr);
    conv_k<<<BT, 256, 0, stream>>>(zx, cwl, cbl, xbc, bcb, xsT);
    dt_k<<<BT * NHEADS / 256, 256, 0, stream>>>(dtraw, dtbl, alogl, dtf, lnAf);
    ssd_intra<<<1024, 256, 0, stream>>>(bcb, xsT, dtf, lnAf, y1buf, SL, dtot);
    ssd_state<<<512, 256, 0, stream>>>(SL, dtot);
    ssd_inter<<<1024, 256, 0, stream>>>(bcb, SL, y1buf, xbc, zx, lnAf, Dwl, yg);
    rms2048_k<<<BT, 256, 0, stream>>>(yg, gwl, yn);
    gemm_pw<1><<<dim3(16, 32), 256, 0, stream>>>(yn, Wol, BT, DIM, DINNER, nullptr, h_f32, hb);
  }

  rmsfinal_k<<<BT, 256, 0, stream>>>(h_f32, fnw, hn);
  gemm_pw<2><<<dim3(4, 32), 256, 0, stream>>>(hn, emb_b, BT, 256, DIM,
                                              nullptr, (float*)d_out, nullptr);
}

// Round 9
// 448.224 us; speedup vs baseline: 1.4910x; 1.1506x over previous
//
#include <hip/hip_runtime.h>
#include <hip/hip_bf16.h>

#define BT 2048
#define T_SEQ 1024
#define DIM 1024
#define DINNER 2048
#define DSTATE 128
#define HEADDIM 64
#define NHEADS 32
#define CONVCH 2304
#define DINPROJ 4384
#define EPS_F 1e-5f
#define NCHUNK 16   // T_SEQ / 64

typedef __bf16 bf16x8 __attribute__((ext_vector_type(8)));
typedef float f32x4 __attribute__((ext_vector_type(4)));

__device__ __forceinline__ float b2f(unsigned short u) {
  union { unsigned int i; float f; } v; v.i = ((unsigned int)u) << 16; return v.f;
}
__device__ __forceinline__ unsigned short f2b(float f) {
  unsigned int x = __float_as_uint(f);
  return (unsigned short)((x + 0x7fffu + ((x >> 16) & 1u)) >> 16);
}

// async global->LDS DMA (gemm staging)
__device__ __forceinline__ void gload_lds16(const void* g, void* l) {
  __builtin_amdgcn_global_load_lds(
      (const __attribute__((address_space(1))) unsigned int*)g,
      (__attribute__((address_space(3))) unsigned int*)l, 16, 0, 0);
}

// ---------------- fp32 -> bf16 weight conversion ----------------
__global__ void cvt_k(const float* __restrict__ in, unsigned short* __restrict__ out, int n) {
  int i = (blockIdx.x * 256 + threadIdx.x) * 4;
  if (i < n) {
    float4 v = *(const float4*)(in + i);
    out[i + 0] = f2b(v.x);
    out[i + 1] = f2b(v.y);
    out[i + 2] = f2b(v.z);
    out[i + 3] = f2b(v.w);
  }
}

// ---------------- embed lookup ----------------
__global__ void embed_k(const int* __restrict__ x, const float* __restrict__ emb,
                        float* __restrict__ h, unsigned short* __restrict__ hb) {
  int t = blockIdx.x;
  int tok = x[t];
  int d = threadIdx.x;
#pragma unroll
  for (int j = 0; j < 4; ++j, d += 256) {
    float v = emb[(size_t)tok * DIM + d];
    h[(size_t)t * DIM + d] = v;
    hb[(size_t)t * DIM + d] = f2b(v);
  }
}

// ---------------- GEMM: C[M,N] = A[M,K] * Bw[N,K]^T (bf16, fp32 acc) ----------------
// Block-shared LDS staging via global_load_lds, 2-barrier K-loop (best-measured
// structure at this size: R5/R6 evidence; flat & per-wave variants regressed).
// gemm0 uses 128x128 (55.6us measured), gemm1/2 use 64x64.
template <int MODE, int TM, int TN>
__global__ __launch_bounds__(256) void gemm_bt(
    const unsigned short* __restrict__ A,
    const unsigned short* __restrict__ Bw,
    int M, int N, int K,
    unsigned short* __restrict__ Cout,
    float* __restrict__ aux,
    unsigned short* __restrict__ aux2) {
  constexpr int FM = TM / 32, FN = TN / 32;
  constexpr int JA = TM / 64, JB = TN / 64;
  __shared__ __align__(16) unsigned short As[TM * 32];
  __shared__ __align__(16) unsigned short Bs[TN * 32];
  const int tid = threadIdx.x;
  const int lane = tid & 63;
  const int wave = tid >> 6;
  const int m0 = blockIdx.y * TM;
  const int n0 = blockIdx.x * TN;
  const int wm = (wave >> 1) * (TM / 2);
  const int wn = (wave & 1) * (TN / 2);
  const int quad = lane >> 4;
  const int r = lane & 15;

  f32x4 acc[FM][FN];
#pragma unroll
  for (int i = 0; i < FM; ++i)
#pragma unroll
    for (int j = 0; j < FN; ++j) acc[i][j] = f32x4{0.f, 0.f, 0.f, 0.f};

  const int rowt = tid >> 2, colt = (tid & 3) * 8;
  const unsigned short* aG[JA];
  unsigned short* aD[JA];
  const unsigned short* bG[JB];
  unsigned short* bD[JB];
#pragma unroll
  for (int j = 0; j < JA; ++j) {
    aG[j] = A + (size_t)(m0 + rowt + j * 64) * K + colt;
    aD[j] = As + wave * 512 + j * 2048;
  }
#pragma unroll
  for (int j = 0; j < JB; ++j) {
    int rb = n0 + rowt + j * 64; if (rb >= N) rb = N - 1;
    bG[j] = Bw + (size_t)rb * K + colt;
    bD[j] = Bs + wave * 512 + j * 2048;
  }

  for (int k0 = 0; k0 < K; k0 += 32) {
    __syncthreads();
#pragma unroll
    for (int j = 0; j < JA; ++j) gload_lds16(aG[j] + k0, aD[j]);
#pragma unroll
    for (int j = 0; j < JB; ++j) gload_lds16(bG[j] + k0, bD[j]);
    __syncthreads();  // drains vmcnt(0) -> staging visible
    const bf16x8* ap = (const bf16x8*)As;
    const bf16x8* bp = (const bf16x8*)Bs;
    bf16x8 af[FM], bfr[FN];
#pragma unroll
    for (int mt = 0; mt < FM; ++mt) af[mt] = ap[(wm + mt * 16 + r) * 4 + quad];
#pragma unroll
    for (int nt = 0; nt < FN; ++nt) bfr[nt] = bp[(wn + nt * 16 + r) * 4 + quad];
#pragma unroll
    for (int mt = 0; mt < FM; ++mt)
#pragma unroll
      for (int nt = 0; nt < FN; ++nt)
        acc[mt][nt] = __builtin_amdgcn_mfma_f32_16x16x32_bf16(af[mt], bfr[nt], acc[mt][nt], 0, 0, 0);
  }

#pragma unroll
  for (int mt = 0; mt < FM; ++mt) {
#pragma unroll
    for (int nt = 0; nt < FN; ++nt) {
#pragma unroll
      for (int i = 0; i < 4; ++i) {
        int gm = m0 + wm + mt * 16 + quad * 4 + i;
        int gn = n0 + wn + nt * 16 + r;
        if (gn < N) {
          float v = acc[mt][nt][i];
          if (MODE == 0) {
            Cout[(size_t)gm * N + gn] = f2b(v);
            if (gn >= DINNER + CONVCH)
              aux[(size_t)gm * NHEADS + (gn - (DINNER + CONVCH))] = v;
          } else if (MODE == 1) {
            size_t o = (size_t)gm * N + gn;
            float hnv = aux[o] + v;
            aux[o] = hnv;
            aux2[o] = f2b(hnv);
          } else {
            aux[(size_t)gm * N + gn] = v;
          }
        }
      }
    }
  }
}

// ---------------- causal conv (K=4) + silu, with fused dt/lnA ----------------
// block = one token t. Also: threads 0-31 compute dt = softplus(dt_raw+bias),
// lnA = -dt*exp(A_log) for this token (fused former dt_k).
__global__ void conv_k(const unsigned short* __restrict__ zx,
                       const float* __restrict__ cw,
                       const float* __restrict__ cb,
                       unsigned short* __restrict__ xbc,
                       unsigned short* __restrict__ bcb,
                       unsigned short* __restrict__ xsT,
                       const float* __restrict__ dtraw,
                       const float* __restrict__ dtb,
                       const float* __restrict__ alog,
                       float* __restrict__ dtf,
                       float* __restrict__ lnAf) {
  int t = blockIdx.x;
  int tt = t & (T_SEQ - 1);
  int b = t >> 10;
  if (threadIdx.x < NHEADS) {
    int h = threadIdx.x;
    float xx = dtraw[t * NHEADS + h] + dtb[h];
    float sp = (xx > 20.f) ? xx : log1pf(expf(xx));
    dtf[t * NHEADS + h] = sp;
    lnAf[t * NHEADS + h] = -sp * expf(alog[h]);
  }
  for (int c = threadIdx.x; c < CONVCH; c += 256) {
    float acc = cb[c];
#pragma unroll
    for (int k = 0; k < 4; ++k) {
      int tp = tt - 3 + k;
      if (tp >= 0)
        acc += b2f(zx[(size_t)(t - 3 + k) * DINPROJ + DINNER + c]) * cw[c * 4 + k];
    }
    float s = acc / (1.f + expf(-acc));
    unsigned short sb = f2b(s);
    xbc[(size_t)t * CONVCH + c] = sb;
    if (c >= DINNER) {
      bcb[(size_t)t * 256 + (c - DINNER)] = sb;
    } else {
      int hh = c >> 6, p = c & 63;
      xsT[(((size_t)b * NHEADS + hh) * HEADDIM + p) * T_SEQ + tt] = sb;
    }
  }
}

// ---------------- SSD pass 1: intra-chunk (per (b,h,chunk)) ----------------
__global__ __launch_bounds__(256) void ssd_intra(
    const unsigned short* __restrict__ bcb,
    const unsigned short* __restrict__ xsT,
    const float* __restrict__ dtf, const float* __restrict__ lnAf,
    unsigned short* __restrict__ y1buf, unsigned short* __restrict__ SL,
    float* __restrict__ dtot) {
  const int bi = blockIdx.x;           // ((b*32+h)*16 + c), 1024 blocks
  const int c = bi & 15;
  const int h = (bi >> 4) & 31;
  const int b = bi >> 9;
  const int tid = threadIdx.x;
  const int w = tid >> 6, l = tid & 63, r = l & 15, quad = l >> 4;
  const size_t tok0 = (size_t)b * T_SEQ + c * 64;

  __shared__ __align__(16) unsigned short BCs[64 * 264];  // [t][B0..127|C128..255]+pad
  __shared__ __align__(16) unsigned short XTs[64 * 72];   // [p][u]
  __shared__ __align__(16) unsigned short XWs[64 * 72];   // [p][u] * ws[u]
  __shared__ __align__(16) unsigned short Ms[64 * 72];    // [t][u]
  __shared__ float cumL[64], dtL[64];

#pragma unroll
  for (int i = 0; i < 8; ++i) {
    int idx = tid + i * 256;
    int row = idx >> 5, col = (idx & 31) * 8;
    uint4 v = *(const uint4*)(bcb + (tok0 + row) * 256 + col);
    *(uint4*)(BCs + row * 264 + col) = v;
  }
  const size_t xtb = ((size_t)(b * NHEADS + h) * HEADDIM) * T_SEQ + c * 64;
#pragma unroll
  for (int i = 0; i < 2; ++i) {
    int idx = tid + i * 256;
    int row = idx >> 3, col = (idx & 7) * 8;
    uint4 v = *(const uint4*)(xsT + xtb + (size_t)row * T_SEQ + col);
    *(uint4*)(XTs + row * 72 + col) = v;
  }
  if (tid < 64) {
    float v = lnAf[(tok0 + tid) * NHEADS + h];
    dtL[tid] = dtf[(tok0 + tid) * NHEADS + h];
#pragma unroll
    for (int off = 1; off < 64; off <<= 1) {
      float u = __shfl_up(v, off, 64);
      if (tid >= off) v += u;
    }
    cumL[tid] = v;
    if (tid == 63) dtot[bi] = expf(v);
  }
  __syncthreads();

  const float cum63 = cumL[63];
#pragma unroll
  for (int i = 0; i < 16; ++i) {
    int idx = tid + i * 256;
    int p = idx >> 6, u = idx & 63;
    float ws = dtL[u] * expf(cum63 - cumL[u]);
    XWs[p * 72 + u] = f2b(b2f(XTs[p * 72 + u]) * ws);
  }

  // GEMM1: G = C·B^T  (64x64, K=128)
  f32x4 g[4];
#pragma unroll
  for (int nt = 0; nt < 4; ++nt) g[nt] = f32x4{0.f, 0.f, 0.f, 0.f};
#pragma unroll
  for (int kk = 0; kk < 4; ++kk) {
    bf16x8 afr = *(const bf16x8*)(BCs + (w * 16 + r) * 264 + 128 + kk * 32 + quad * 8);
#pragma unroll
    for (int nt = 0; nt < 4; ++nt) {
      bf16x8 bfr = *(const bf16x8*)(BCs + (nt * 16 + r) * 264 + kk * 32 + quad * 8);
      g[nt] = __builtin_amdgcn_mfma_f32_16x16x32_bf16(afr, bfr, g[nt], 0, 0, 0);
    }
  }
#pragma unroll
  for (int nt = 0; nt < 4; ++nt) {
#pragma unroll
    for (int i = 0; i < 4; ++i) {
      int t_ = w * 16 + quad * 4 + i;
      int u_ = nt * 16 + r;
      float wv = (u_ <= t_) ? expf(cumL[t_] - cumL[u_]) * dtL[u_] : 0.f;
      Ms[t_ * 72 + u_] = f2b(g[nt][i] * wv);
    }
  }
  __syncthreads();

  // GEMM2: Y1 = M·X  (64t x 64p, K=64u)
  f32x4 y1[4];
#pragma unroll
  for (int nt = 0; nt < 4; ++nt) y1[nt] = f32x4{0.f, 0.f, 0.f, 0.f};
#pragma unroll
  for (int kk = 0; kk < 2; ++kk) {
    bf16x8 afr = *(const bf16x8*)(Ms + (w * 16 + r) * 72 + kk * 32 + quad * 8);
#pragma unroll
    for (int nt = 0; nt < 4; ++nt) {
      bf16x8 bfr = *(const bf16x8*)(XTs + (nt * 16 + r) * 72 + kk * 32 + quad * 8);
      y1[nt] = __builtin_amdgcn_mfma_f32_16x16x32_bf16(afr, bfr, y1[nt], 0, 0, 0);
    }
  }
#pragma unroll
  for (int nt = 0; nt < 4; ++nt)
#pragma unroll
    for (int i = 0; i < 4; ++i) {
      int t_ = w * 16 + quad * 4 + i, p_ = nt * 16 + r;
      y1buf[((size_t)bi * 64 + t_) * 64 + p_] = f2b(y1[nt][i]);
    }

  // GEMM3: Slocal = XW·B  (64p x 128n, K=64u); B-operand frag built transposed
  f32x4 sl[8];
#pragma unroll
  for (int nt = 0; nt < 8; ++nt) sl[nt] = f32x4{0.f, 0.f, 0.f, 0.f};
#pragma unroll
  for (int kk = 0; kk < 2; ++kk) {
    bf16x8 afr = *(const bf16x8*)(XWs + (w * 16 + r) * 72 + kk * 32 + quad * 8);
#pragma unroll
    for (int nt = 0; nt < 8; ++nt) {
      union { bf16x8 v; unsigned short u[8]; } bq;
#pragma unroll
      for (int j = 0; j < 8; ++j)
        bq.u[j] = BCs[(kk * 32 + quad * 8 + j) * 264 + nt * 16 + r];
      sl[nt] = __builtin_amdgcn_mfma_f32_16x16x32_bf16(afr, bq.v, sl[nt], 0, 0, 0);
    }
  }
#pragma unroll
  for (int nt = 0; nt < 8; ++nt)
#pragma unroll
    for (int i = 0; i < 4; ++i) {
      int p_ = w * 16 + quad * 4 + i, n_ = nt * 16 + r;
      SL[((size_t)bi * 64 + p_) * 128 + n_] = f2b(sl[nt][i]);
    }
}

// ---------------- SSD pass 2: chunk-state recurrence (in-place Slocal -> Spre) --------
__global__ void ssd_state(unsigned short* __restrict__ SL,
                          const float* __restrict__ dtot) {
  int gidx = blockIdx.x * 256 + threadIdx.x;   // 131072 = 64bh * 64p * 32(n/4)
  int n4 = (gidx & 31) * 4;
  int p = (gidx >> 5) & 63;
  int bh = gidx >> 11;
  float sx = 0.f, sy = 0.f, sz = 0.f, sw = 0.f;
  for (int c = 0; c < NCHUNK; ++c) {
    size_t off = ((size_t)(bh * 16 + c) * 64 + p) * 128 + n4;
    uint2 lv = *(uint2*)(SL + off);
    float d = dtot[bh * 16 + c];
    uint2 sv;
    sv.x = (unsigned)f2b(sx) | ((unsigned)f2b(sy) << 16);
    sv.y = (unsigned)f2b(sz) | ((unsigned)f2b(sw) << 16);
    *(uint2*)(SL + off) = sv;           // state BEFORE chunk c
    sx = d * sx + b2f(lv.x & 0xffff);
    sy = d * sy + b2f(lv.x >> 16);
    sz = d * sz + b2f(lv.y & 0xffff);
    sw = d * sw + b2f(lv.y >> 16);
  }
}

// ---------------- SSD pass 3: inter-chunk + combine + gate ----------------
__global__ __launch_bounds__(256) void ssd_inter(
    const unsigned short* __restrict__ bcb,
    const unsigned short* __restrict__ SL,       // holds Spre now
    const unsigned short* __restrict__ y1buf,
    const unsigned short* __restrict__ xbc,
    const unsigned short* __restrict__ zx,
    const float* __restrict__ lnAf,
    const float* __restrict__ Dw,
    unsigned short* __restrict__ yg) {
  const int bi = blockIdx.x;
  const int c = bi & 15, h = (bi >> 4) & 31, b = bi >> 9;
  const int tid = threadIdx.x;
  const int w = tid >> 6, l = tid & 63, r = l & 15, quad = l >> 4;
  const size_t tok0 = (size_t)b * T_SEQ + c * 64;

  __shared__ __align__(16) unsigned short Cs[64 * 136];
  __shared__ __align__(16) unsigned short Sp[64 * 136];
  __shared__ __align__(16) float Yf[64 * 68];
  __shared__ float cumL[64];

#pragma unroll
  for (int i = 0; i < 4; ++i) {
    int idx = tid + i * 256;
    int row = idx >> 4, col = (idx & 15) * 8;
    uint4 v = *(const uint4*)(bcb + (tok0 + row) * 256 + 128 + col);
    *(uint4*)(Cs + row * 136 + col) = v;
    uint4 s = *(const uint4*)(SL + ((size_t)bi * 64 + row) * 128 + col);
    *(uint4*)(Sp + row * 136 + col) = s;
  }
  if (tid < 64) {
    float v = lnAf[(tok0 + tid) * NHEADS + h];
#pragma unroll
    for (int off = 1; off < 64; off <<= 1) {
      float u = __shfl_up(v, off, 64);
      if (tid >= off) v += u;
    }
    cumL[tid] = v;
  }
  __syncthreads();

  // Yi[t][p] = sum_n C[t][n]*Spre[p][n]  (K=128)
  f32x4 yi[4];
#pragma unroll
  for (int nt = 0; nt < 4; ++nt) yi[nt] = f32x4{0.f, 0.f, 0.f, 0.f};
#pragma unroll
  for (int kk = 0; kk < 4; ++kk) {
    bf16x8 afr = *(const bf16x8*)(Cs + (w * 16 + r) * 136 + kk * 32 + quad * 8);
#pragma unroll
    for (int nt = 0; nt < 4; ++nt) {
      bf16x8 bfr = *(const bf16x8*)(Sp + (nt * 16 + r) * 136 + kk * 32 + quad * 8);
      yi[nt] = __builtin_amdgcn_mfma_f32_16x16x32_bf16(afr, bfr, yi[nt], 0, 0, 0);
    }
  }
#pragma unroll
  for (int nt = 0; nt < 4; ++nt)
#pragma unroll
    for (int i = 0; i < 4; ++i) {
      int t_ = w * 16 + quad * 4 + i, p_ = nt * 16 + r;
      float y1 = b2f(y1buf[((size_t)bi * 64 + t_) * 64 + p_]);
      Yf[t_ * 68 + p_] = y1 + expf(cumL[t_]) * yi[nt][i];
    }
  __syncthreads();

  // combine: y = Yf + D*x, gate with silu(z), write yg
  const float Dh = Dw[h];
  const int t_ = tid >> 2, pg = (tid & 3) * 16;
  const size_t tok = tok0 + t_;
  union { uint4 q[2]; unsigned short u[16]; } xv, zv, ov;
  xv.q[0] = *(const uint4*)(xbc + tok * CONVCH + h * 64 + pg);
  xv.q[1] = *(const uint4*)(xbc + tok * CONVCH + h * 64 + pg + 8);
  zv.q[0] = *(const uint4*)(zx + tok * DINPROJ + h * 64 + pg);
  zv.q[1] = *(const uint4*)(zx + tok * DINPROJ + h * 64 + pg + 8);
#pragma unroll
  for (int j = 0; j < 16; ++j) {
    float y = Yf[t_ * 68 + pg + j] + Dh * b2f(xv.u[j]);
    float zf = b2f(zv.u[j]);
    ov.u[j] = f2b(y * (zf / (1.f + expf(-zf))));
  }
  *(uint4*)(yg + tok * DINNER + h * 64 + pg) = ov.q[0];
  *(uint4*)(yg + tok * DINNER + h * 64 + pg + 8) = ov.q[1];
}

// ---------------- RMSNorm over 2048 ----------------
__global__ void rms2048_k(const unsigned short* __restrict__ in,
                          const float* __restrict__ w,
                          unsigned short* __restrict__ out) {
  int t = blockIdx.x;
  int base = threadIdx.x * 8;
  union { uint4 q; unsigned short u[8]; } vv;
  vv.q = *(const uint4*)(in + (size_t)t * DINNER + base);
  float f[8];
  float ss = 0.f;
#pragma unroll
  for (int j = 0; j < 8; ++j) { f[j] = b2f(vv.u[j]); ss += f[j] * f[j]; }
#pragma unroll
  for (int o = 32; o > 0; o >>= 1) ss += __shfl_xor(ss, o, 64);
  __shared__ float red[4];
  if ((threadIdx.x & 63) == 0) red[threadIdx.x >> 6] = ss;
  __syncthreads();
  ss = red[0] + red[1] + red[2] + red[3];
  float scale = rsqrtf(ss * (1.f / DINNER) + EPS_F);
#pragma unroll
  for (int j = 0; j < 8; ++j)
    out[(size_t)t * DINNER + base + j] = f2b(f[j] * scale * w[base + j]);
}

// ---------------- final RMSNorm over 1024 ----------------
__global__ void rmsfinal_k(const float* __restrict__ hf,
                           const float* __restrict__ w,
                           unsigned short* __restrict__ out) {
  int t = blockIdx.x;
  int base = threadIdx.x * 4;
  float4 v = *(const float4*)(hf + (size_t)t * DIM + base);
  float ss = v.x * v.x + v.y * v.y + v.z * v.z + v.w * v.w;
#pragma unroll
  for (int o = 32; o > 0; o >>= 1) ss += __shfl_xor(ss, o, 64);
  __shared__ float red[4];
  if ((threadIdx.x & 63) == 0) red[threadIdx.x >> 6] = ss;
  __syncthreads();
  ss = red[0] + red[1] + red[2] + red[3];
  float scale = rsqrtf(ss * (1.f / DIM) + EPS_F);
  out[(size_t)t * DIM + base + 0] = f2b(v.x * scale * w[base + 0]);
  out[(size_t)t * DIM + base + 1] = f2b(v.y * scale * w[base + 1]);
  out[(size_t)t * DIM + base + 2] = f2b(v.z * scale * w[base + 2]);
  out[(size_t)t * DIM + base + 3] = f2b(v.w * scale * w[base + 3]);
}

extern "C" void kernel_launch(void* const* d_in, const int* in_sizes, int n_in,
                              void* d_out, int out_size, void* d_ws, size_t ws_size,
                              hipStream_t stream) {
  const int*   x    = (const int*)d_in[0];
  const float* emb  = (const float*)d_in[1];
  const float* Wp   = (const float*)d_in[2];
  const float* cw   = (const float*)d_in[3];
  const float* cb   = (const float*)d_in[4];
  const float* dtb  = (const float*)d_in[5];
  const float* alog = (const float*)d_in[6];
  const float* Dw   = (const float*)d_in[7];
  const float* gw   = (const float*)d_in[8];
  const float* Wo   = (const float*)d_in[9];
  const float* fnw  = (const float*)d_in[10];

  char* w = (char*)d_ws;
  auto alloc = [&](size_t bytes) {
    char* p = w; w += (bytes + 255) & ~(size_t)255; return p;
  };
  float* h_f32          = (float*)alloc((size_t)BT * DIM * 4);
  unsigned short* hb    = (unsigned short*)alloc((size_t)BT * DIM * 2);
  unsigned short* zx    = (unsigned short*)alloc((size_t)BT * DINPROJ * 2);
  float* dtraw          = (float*)alloc((size_t)BT * NHEADS * 4);
  float* dtf            = (float*)alloc((size_t)BT * NHEADS * 4);
  float* lnAf           = (float*)alloc((size_t)BT * NHEADS * 4);
  unsigned short* xbc   = (unsigned short*)alloc((size_t)BT * CONVCH * 2);
  unsigned short* bcb   = (unsigned short*)alloc((size_t)BT * 256 * 2);
  unsigned short* xsT   = (unsigned short*)alloc((size_t)BT * DINNER * 2);
  unsigned short* SL    = (unsigned short*)alloc((size_t)1024 * 64 * 128 * 2);
  unsigned short* y1buf = (unsigned short*)alloc((size_t)1024 * 64 * 64 * 2);
  float* dtot           = (float*)alloc((size_t)1024 * 4);
  unsigned short* yg    = (unsigned short*)alloc((size_t)BT * DINNER * 2);
  unsigned short* yn    = (unsigned short*)alloc((size_t)BT * DINNER * 2);
  unsigned short* hn    = (unsigned short*)alloc((size_t)BT * DIM * 2);
  unsigned short* Wp_b  = (unsigned short*)alloc((size_t)2 * DINPROJ * DIM * 2);
  unsigned short* Wo_b  = (unsigned short*)alloc((size_t)2 * DIM * DINNER * 2);
  unsigned short* emb_b = (unsigned short*)alloc((size_t)256 * DIM * 2 + 256);

  {
    int nWp = 2 * DINPROJ * DIM;
    int nWo = 2 * DIM * DINNER;
    int nEm = 256 * DIM;
    cvt_k<<<(nWp / 4 + 255) / 256, 256, 0, stream>>>(Wp, Wp_b, nWp);
    cvt_k<<<(nWo / 4 + 255) / 256, 256, 0, stream>>>(Wo, Wo_b, nWo);
    cvt_k<<<(nEm / 4 + 255) / 256, 256, 0, stream>>>(emb, emb_b, nEm);
  }

  embed_k<<<BT, 256, 0, stream>>>(x, emb, h_f32, hb);

  for (int l = 0; l < 2; ++l) {
    const unsigned short* Wpl = Wp_b + (size_t)l * DINPROJ * DIM;
    const unsigned short* Wol = Wo_b + (size_t)l * DIM * DINNER;
    const float* cwl   = cw + (size_t)l * CONVCH * 4;
    const float* cbl   = cb + (size_t)l * CONVCH;
    const float* dtbl  = dtb + l * NHEADS;
    const float* alogl = alog + l * NHEADS;
    const float* Dwl   = Dw + l * NHEADS;
    const float* gwl   = gw + (size_t)l * DINNER;

    gemm_bt<0, 128, 128><<<dim3(35, 16), 256, 0, stream>>>(hb, Wpl, BT, DINPROJ, DIM, zx, dtraw, nullptr);
    conv_k<<<BT, 256, 0, stream>>>(zx, cwl, cbl, xbc, bcb, xsT, dtraw, dtbl, alogl, dtf, lnAf);
    ssd_intra<<<1024, 256, 0, stream>>>(bcb, xsT, dtf, lnAf, y1buf, SL, dtot);
    ssd_state<<<512, 256, 0, stream>>>(SL, dtot);
    ssd_inter<<<1024, 256, 0, stream>>>(bcb, SL, y1buf, xbc, zx, lnAf, Dwl, yg);
    rms2048_k<<<BT, 256, 0, stream>>>(yg, gwl, yn);
    gemm_bt<1, 64, 64><<<dim3(16, 32), 256, 0, stream>>>(yn, Wol, BT, DIM, DINNER, nullptr, h_f32, hb);
  }

  rmsfinal_k<<<BT, 256, 0, stream>>>(h_f32, fnw, hn);
  gemm_bt<2, 64, 64><<<dim3(4, 32), 256, 0, stream>>>(hn, emb_b, BT, 256, DIM,
                                                      nullptr, (float*)d_out, nullptr);
}

// Round 10
// 403.818 us; speedup vs baseline: 1.6550x; 1.1100x over previous
//
#include <hip/hip_runtime.h>
#include <hip/hip_bf16.h>

#define BT 2048
#define T_SEQ 1024
#define DIM 1024
#define DINNER 2048
#define DSTATE 128
#define HEADDIM 64
#define NHEADS 32
#define CONVCH 2304
#define DINPROJ 4384
#define EPS_F 1e-5f
#define NCHUNK 16   // T_SEQ / 64

typedef __bf16 bf16x8 __attribute__((ext_vector_type(8)));
typedef float f32x4 __attribute__((ext_vector_type(4)));

__device__ __forceinline__ float b2f(unsigned short u) {
  union { unsigned int i; float f; } v; v.i = ((unsigned int)u) << 16; return v.f;
}
__device__ __forceinline__ unsigned short f2b(float f) {
  unsigned int x = __float_as_uint(f);
  return (unsigned short)((x + 0x7fffu + ((x >> 16) & 1u)) >> 16);
}

// async global->LDS DMA (gemm staging)
__device__ __forceinline__ void gload_lds16(const void* g, void* l) {
  __builtin_amdgcn_global_load_lds(
      (const __attribute__((address_space(1))) unsigned int*)g,
      (__attribute__((address_space(3))) unsigned int*)l, 16, 0, 0);
}

// ---------------- fp32 -> bf16 weight conversion ----------------
__global__ void cvt_k(const float* __restrict__ in, unsigned short* __restrict__ out, int n) {
  int i = (blockIdx.x * 256 + threadIdx.x) * 4;
  if (i < n) {
    float4 v = *(const float4*)(in + i);
    out[i + 0] = f2b(v.x);
    out[i + 1] = f2b(v.y);
    out[i + 2] = f2b(v.z);
    out[i + 3] = f2b(v.w);
  }
}

// ---------------- embed lookup ----------------
__global__ void embed_k(const int* __restrict__ x, const float* __restrict__ emb,
                        float* __restrict__ h, unsigned short* __restrict__ hb) {
  int t = blockIdx.x;
  int tok = x[t];
  int d = threadIdx.x;
#pragma unroll
  for (int j = 0; j < 4; ++j, d += 256) {
    float v = emb[(size_t)tok * DIM + d];
    h[(size_t)t * DIM + d] = v;
    hb[(size_t)t * DIM + d] = f2b(v);
  }
}

// ---------------- GEMM: C[M,N] = A[M,K] * Bw[N,K]^T (bf16, fp32 acc) ----------------
// Block-shared LDS staging via global_load_lds, 2-barrier K-loop (best-measured
// structure at this size; flat & per-wave variants regressed).
template <int MODE, int TM, int TN>
__global__ __launch_bounds__(256) void gemm_bt(
    const unsigned short* __restrict__ A,
    const unsigned short* __restrict__ Bw,
    int M, int N, int K,
    unsigned short* __restrict__ Cout,
    float* __restrict__ aux,
    unsigned short* __restrict__ aux2) {
  constexpr int FM = TM / 32, FN = TN / 32;
  constexpr int JA = TM / 64, JB = TN / 64;
  __shared__ __align__(16) unsigned short As[TM * 32];
  __shared__ __align__(16) unsigned short Bs[TN * 32];
  const int tid = threadIdx.x;
  const int lane = tid & 63;
  const int wave = tid >> 6;
  const int m0 = blockIdx.y * TM;
  const int n0 = blockIdx.x * TN;
  const int wm = (wave >> 1) * (TM / 2);
  const int wn = (wave & 1) * (TN / 2);
  const int quad = lane >> 4;
  const int r = lane & 15;

  f32x4 acc[FM][FN];
#pragma unroll
  for (int i = 0; i < FM; ++i)
#pragma unroll
    for (int j = 0; j < FN; ++j) acc[i][j] = f32x4{0.f, 0.f, 0.f, 0.f};

  const int rowt = tid >> 2, colt = (tid & 3) * 8;
  const unsigned short* aG[JA];
  unsigned short* aD[JA];
  const unsigned short* bG[JB];
  unsigned short* bD[JB];
#pragma unroll
  for (int j = 0; j < JA; ++j) {
    aG[j] = A + (size_t)(m0 + rowt + j * 64) * K + colt;
    aD[j] = As + wave * 512 + j * 2048;
  }
#pragma unroll
  for (int j = 0; j < JB; ++j) {
    int rb = n0 + rowt + j * 64; if (rb >= N) rb = N - 1;
    bG[j] = Bw + (size_t)rb * K + colt;
    bD[j] = Bs + wave * 512 + j * 2048;
  }

  for (int k0 = 0; k0 < K; k0 += 32) {
    __syncthreads();
#pragma unroll
    for (int j = 0; j < JA; ++j) gload_lds16(aG[j] + k0, aD[j]);
#pragma unroll
    for (int j = 0; j < JB; ++j) gload_lds16(bG[j] + k0, bD[j]);
    __syncthreads();  // drains vmcnt(0) -> staging visible
    const bf16x8* ap = (const bf16x8*)As;
    const bf16x8* bp = (const bf16x8*)Bs;
    bf16x8 af[FM], bfr[FN];
#pragma unroll
    for (int mt = 0; mt < FM; ++mt) af[mt] = ap[(wm + mt * 16 + r) * 4 + quad];
#pragma unroll
    for (int nt = 0; nt < FN; ++nt) bfr[nt] = bp[(wn + nt * 16 + r) * 4 + quad];
#pragma unroll
    for (int mt = 0; mt < FM; ++mt)
#pragma unroll
      for (int nt = 0; nt < FN; ++nt)
        acc[mt][nt] = __builtin_amdgcn_mfma_f32_16x16x32_bf16(af[mt], bfr[nt], acc[mt][nt], 0, 0, 0);
  }

#pragma unroll
  for (int mt = 0; mt < FM; ++mt) {
#pragma unroll
    for (int nt = 0; nt < FN; ++nt) {
#pragma unroll
      for (int i = 0; i < 4; ++i) {
        int gm = m0 + wm + mt * 16 + quad * 4 + i;
        int gn = n0 + wn + nt * 16 + r;
        if (gn < N) {
          float v = acc[mt][nt][i];
          if (MODE == 0) {
            Cout[(size_t)gm * N + gn] = f2b(v);
            if (gn >= DINNER + CONVCH)
              aux[(size_t)gm * NHEADS + (gn - (DINNER + CONVCH))] = v;
          } else if (MODE == 1) {
            size_t o = (size_t)gm * N + gn;
            float hnv = aux[o] + v;
            aux[o] = hnv;
            aux2[o] = f2b(hnv);
          } else {
            aux[(size_t)gm * N + gn] = v;
          }
        }
      }
    }
  }
}

// ---------------- causal conv (K=4) + silu, with fused dt/lnA ----------------
// NO transposed xsT store (R9: it caused 7x write amplification, 79MB vs 11MB;
// ssd_intra now transposes x in LDS from xbc instead).
__global__ void conv_k(const unsigned short* __restrict__ zx,
                       const float* __restrict__ cw,
                       const float* __restrict__ cb,
                       unsigned short* __restrict__ xbc,
                       unsigned short* __restrict__ bcb,
                       const float* __restrict__ dtraw,
                       const float* __restrict__ dtb,
                       const float* __restrict__ alog,
                       float* __restrict__ dtf,
                       float* __restrict__ lnAf) {
  int t = blockIdx.x;
  int tt = t & (T_SEQ - 1);
  if (threadIdx.x < NHEADS) {
    int h = threadIdx.x;
    float xx = dtraw[t * NHEADS + h] + dtb[h];
    float sp = (xx > 20.f) ? xx : log1pf(expf(xx));
    dtf[t * NHEADS + h] = sp;
    lnAf[t * NHEADS + h] = -sp * expf(alog[h]);
  }
  for (int c = threadIdx.x; c < CONVCH; c += 256) {
    float acc = cb[c];
#pragma unroll
    for (int k = 0; k < 4; ++k) {
      int tp = tt - 3 + k;
      if (tp >= 0)
        acc += b2f(zx[(size_t)(t - 3 + k) * DINPROJ + DINNER + c]) * cw[c * 4 + k];
    }
    float s = acc / (1.f + expf(-acc));
    unsigned short sb = f2b(s);
    xbc[(size_t)t * CONVCH + c] = sb;
    if (c >= DINNER) bcb[(size_t)t * 256 + (c - DINNER)] = sb;
  }
}

// ---------------- SSD pass 1: intra-chunk (per (b,h,chunk)) ----------------
__global__ __launch_bounds__(256) void ssd_intra(
    const unsigned short* __restrict__ bcb,
    const unsigned short* __restrict__ xbc,
    const float* __restrict__ dtf, const float* __restrict__ lnAf,
    unsigned short* __restrict__ y1buf, unsigned short* __restrict__ SL,
    float* __restrict__ dtot) {
  const int bi = blockIdx.x;           // ((b*32+h)*16 + c), 1024 blocks
  const int c = bi & 15;
  const int h = (bi >> 4) & 31;
  const int b = bi >> 9;
  const int tid = threadIdx.x;
  const int w = tid >> 6, l = tid & 63, r = l & 15, quad = l >> 4;
  const size_t tok0 = (size_t)b * T_SEQ + c * 64;

  __shared__ __align__(16) unsigned short BCs[64 * 264];  // [t][B0..127|C128..255]+pad
  __shared__ __align__(16) unsigned short Xrow[64 * 72];  // [u][p] (row-major from xbc)
  __shared__ __align__(16) unsigned short XTs[64 * 72];   // [p][u]
  __shared__ __align__(16) unsigned short XWs[64 * 72];   // [p][u] * ws[u]
  __shared__ __align__(16) unsigned short Ms[64 * 72];    // [t][u]
  __shared__ float cumL[64], dtL[64];

#pragma unroll
  for (int i = 0; i < 8; ++i) {
    int idx = tid + i * 256;
    int row = idx >> 5, col = (idx & 31) * 8;
    uint4 v = *(const uint4*)(bcb + (tok0 + row) * 256 + col);
    *(uint4*)(BCs + row * 264 + col) = v;
  }
  // x tile: rows = tokens (coalesced 128B from xbc), cols = p
#pragma unroll
  for (int i = 0; i < 2; ++i) {
    int idx = tid + i * 256;
    int u = idx >> 3, pc = (idx & 7) * 8;
    uint4 v = *(const uint4*)(xbc + (tok0 + u) * CONVCH + h * HEADDIM + pc);
    *(uint4*)(Xrow + u * 72 + pc) = v;
  }
  if (tid < 64) {
    float v = lnAf[(tok0 + tid) * NHEADS + h];
    dtL[tid] = dtf[(tok0 + tid) * NHEADS + h];
#pragma unroll
    for (int off = 1; off < 64; off <<= 1) {
      float u = __shfl_up(v, off, 64);
      if (tid >= off) v += u;
    }
    cumL[tid] = v;
    if (tid == 63) dtot[bi] = expf(v);
  }
  __syncthreads();

  // in-LDS transpose fused with decay weighting: XTs[p][u] = x, XWs[p][u] = x*ws[u]
  const float cum63 = cumL[63];
#pragma unroll
  for (int i = 0; i < 2; ++i) {
    int idx = tid + i * 256;
    int p = idx >> 3, ug = (idx & 7) * 8;
    unsigned short tA[8], tW[8];
#pragma unroll
    for (int j = 0; j < 8; ++j) {
      unsigned short xv = Xrow[(ug + j) * 72 + p];
      tA[j] = xv;
      float ws = dtL[ug + j] * expf(cum63 - cumL[ug + j]);
      tW[j] = f2b(b2f(xv) * ws);
    }
    *(uint4*)(XTs + p * 72 + ug) = *(uint4*)tA;
    *(uint4*)(XWs + p * 72 + ug) = *(uint4*)tW;
  }

  // GEMM1: G = C·B^T  (64x64, K=128)
  f32x4 g[4];
#pragma unroll
  for (int nt = 0; nt < 4; ++nt) g[nt] = f32x4{0.f, 0.f, 0.f, 0.f};
#pragma unroll
  for (int kk = 0; kk < 4; ++kk) {
    bf16x8 afr = *(const bf16x8*)(BCs + (w * 16 + r) * 264 + 128 + kk * 32 + quad * 8);
#pragma unroll
    for (int nt = 0; nt < 4; ++nt) {
      bf16x8 bfr = *(const bf16x8*)(BCs + (nt * 16 + r) * 264 + kk * 32 + quad * 8);
      g[nt] = __builtin_amdgcn_mfma_f32_16x16x32_bf16(afr, bfr, g[nt], 0, 0, 0);
    }
  }
#pragma unroll
  for (int nt = 0; nt < 4; ++nt) {
#pragma unroll
    for (int i = 0; i < 4; ++i) {
      int t_ = w * 16 + quad * 4 + i;
      int u_ = nt * 16 + r;
      float wv = (u_ <= t_) ? expf(cumL[t_] - cumL[u_]) * dtL[u_] : 0.f;
      Ms[t_ * 72 + u_] = f2b(g[nt][i] * wv);
    }
  }
  __syncthreads();

  // GEMM2: Y1 = M·X  (64t x 64p, K=64u)
  f32x4 y1[4];
#pragma unroll
  for (int nt = 0; nt < 4; ++nt) y1[nt] = f32x4{0.f, 0.f, 0.f, 0.f};
#pragma unroll
  for (int kk = 0; kk < 2; ++kk) {
    bf16x8 afr = *(const bf16x8*)(Ms + (w * 16 + r) * 72 + kk * 32 + quad * 8);
#pragma unroll
    for (int nt = 0; nt < 4; ++nt) {
      bf16x8 bfr = *(const bf16x8*)(XTs + (nt * 16 + r) * 72 + kk * 32 + quad * 8);
      y1[nt] = __builtin_amdgcn_mfma_f32_16x16x32_bf16(afr, bfr, y1[nt], 0, 0, 0);
    }
  }
#pragma unroll
  for (int nt = 0; nt < 4; ++nt)
#pragma unroll
    for (int i = 0; i < 4; ++i) {
      int t_ = w * 16 + quad * 4 + i, p_ = nt * 16 + r;
      y1buf[((size_t)bi * 64 + t_) * 64 + p_] = f2b(y1[nt][i]);
    }

  // GEMM3: Slocal = XW·B  (64p x 128n, K=64u); B-operand frag built transposed
  f32x4 sl[8];
#pragma unroll
  for (int nt = 0; nt < 8; ++nt) sl[nt] = f32x4{0.f, 0.f, 0.f, 0.f};
#pragma unroll
  for (int kk = 0; kk < 2; ++kk) {
    bf16x8 afr = *(const bf16x8*)(XWs + (w * 16 + r) * 72 + kk * 32 + quad * 8);
#pragma unroll
    for (int nt = 0; nt < 8; ++nt) {
      union { bf16x8 v; unsigned short u[8]; } bq;
#pragma unroll
      for (int j = 0; j < 8; ++j)
        bq.u[j] = BCs[(kk * 32 + quad * 8 + j) * 264 + nt * 16 + r];
      sl[nt] = __builtin_amdgcn_mfma_f32_16x16x32_bf16(afr, bq.v, sl[nt], 0, 0, 0);
    }
  }
#pragma unroll
  for (int nt = 0; nt < 8; ++nt)
#pragma unroll
    for (int i = 0; i < 4; ++i) {
      int p_ = w * 16 + quad * 4 + i, n_ = nt * 16 + r;
      SL[((size_t)bi * 64 + p_) * 128 + n_] = f2b(sl[nt][i]);
    }
}

// ---------------- SSD pass 2: chunk-state recurrence (in-place Slocal -> Spre) --------
__global__ void ssd_state(unsigned short* __restrict__ SL,
                          const float* __restrict__ dtot) {
  int gidx = blockIdx.x * 256 + threadIdx.x;   // 131072 = 64bh * 64p * 32(n/4)
  int n4 = (gidx & 31) * 4;
  int p = (gidx >> 5) & 63;
  int bh = gidx >> 11;
  float sx = 0.f, sy = 0.f, sz = 0.f, sw = 0.f;
  for (int c = 0; c < NCHUNK; ++c) {
    size_t off = ((size_t)(bh * 16 + c) * 64 + p) * 128 + n4;
    uint2 lv = *(uint2*)(SL + off);
    float d = dtot[bh * 16 + c];
    uint2 sv;
    sv.x = (unsigned)f2b(sx) | ((unsigned)f2b(sy) << 16);
    sv.y = (unsigned)f2b(sz) | ((unsigned)f2b(sw) << 16);
    *(uint2*)(SL + off) = sv;           // state BEFORE chunk c
    sx = d * sx + b2f(lv.x & 0xffff);
    sy = d * sy + b2f(lv.x >> 16);
    sz = d * sz + b2f(lv.y & 0xffff);
    sw = d * sw + b2f(lv.y >> 16);
  }
}

// ---------------- SSD pass 3: inter-chunk + combine + gate ----------------
__global__ __launch_bounds__(256) void ssd_inter(
    const unsigned short* __restrict__ bcb,
    const unsigned short* __restrict__ SL,       // holds Spre now
    const unsigned short* __restrict__ y1buf,
    const unsigned short* __restrict__ xbc,
    const unsigned short* __restrict__ zx,
    const float* __restrict__ lnAf,
    const float* __restrict__ Dw,
    unsigned short* __restrict__ yg) {
  const int bi = blockIdx.x;
  const int c = bi & 15, h = (bi >> 4) & 31, b = bi >> 9;
  const int tid = threadIdx.x;
  const int w = tid >> 6, l = tid & 63, r = l & 15, quad = l >> 4;
  const size_t tok0 = (size_t)b * T_SEQ + c * 64;

  __shared__ __align__(16) unsigned short Cs[64 * 136];
  __shared__ __align__(16) unsigned short Sp[64 * 136];
  __shared__ __align__(16) float Yf[64 * 68];
  __shared__ float cumL[64];

#pragma unroll
  for (int i = 0; i < 4; ++i) {
    int idx = tid + i * 256;
    int row = idx >> 4, col = (idx & 15) * 8;
    uint4 v = *(const uint4*)(bcb + (tok0 + row) * 256 + 128 + col);
    *(uint4*)(Cs + row * 136 + col) = v;
    uint4 s = *(const uint4*)(SL + ((size_t)bi * 64 + row) * 128 + col);
    *(uint4*)(Sp + row * 136 + col) = s;
  }
  if (tid < 64) {
    float v = lnAf[(tok0 + tid) * NHEADS + h];
#pragma unroll
    for (int off = 1; off < 64; off <<= 1) {
      float u = __shfl_up(v, off, 64);
      if (tid >= off) v += u;
    }
    cumL[tid] = v;
  }
  __syncthreads();

  // Yi[t][p] = sum_n C[t][n]*Spre[p][n]  (K=128)
  f32x4 yi[4];
#pragma unroll
  for (int nt = 0; nt < 4; ++nt) yi[nt] = f32x4{0.f, 0.f, 0.f, 0.f};
#pragma unroll
  for (int kk = 0; kk < 4; ++kk) {
    bf16x8 afr = *(const bf16x8*)(Cs + (w * 16 + r) * 136 + kk * 32 + quad * 8);
#pragma unroll
    for (int nt = 0; nt < 4; ++nt) {
      bf16x8 bfr = *(const bf16x8*)(Sp + (nt * 16 + r) * 136 + kk * 32 + quad * 8);
      yi[nt] = __builtin_amdgcn_mfma_f32_16x16x32_bf16(afr, bfr, yi[nt], 0, 0, 0);
    }
  }
#pragma unroll
  for (int nt = 0; nt < 4; ++nt)
#pragma unroll
    for (int i = 0; i < 4; ++i) {
      int t_ = w * 16 + quad * 4 + i, p_ = nt * 16 + r;
      float y1 = b2f(y1buf[((size_t)bi * 64 + t_) * 64 + p_]);
      Yf[t_ * 68 + p_] = y1 + expf(cumL[t_]) * yi[nt][i];
    }
  __syncthreads();

  // combine: y = Yf + D*x, gate with silu(z), write yg
  const float Dh = Dw[h];
  const int t_ = tid >> 2, pg = (tid & 3) * 16;
  const size_t tok = tok0 + t_;
  union { uint4 q[2]; unsigned short u[16]; } xv, zv, ov;
  xv.q[0] = *(const uint4*)(xbc + tok * CONVCH + h * 64 + pg);
  xv.q[1] = *(const uint4*)(xbc + tok * CONVCH + h * 64 + pg + 8);
  zv.q[0] = *(const uint4*)(zx + tok * DINPROJ + h * 64 + pg);
  zv.q[1] = *(const uint4*)(zx + tok * DINPROJ + h * 64 + pg + 8);
#pragma unroll
  for (int j = 0; j < 16; ++j) {
    float y = Yf[t_ * 68 + pg + j] + Dh * b2f(xv.u[j]);
    float zf = b2f(zv.u[j]);
    ov.u[j] = f2b(y * (zf / (1.f + expf(-zf))));
  }
  *(uint4*)(yg + tok * DINNER + h * 64 + pg) = ov.q[0];
  *(uint4*)(yg + tok * DINNER + h * 64 + pg + 8) = ov.q[1];
}

// ---------------- RMSNorm over 2048 ----------------
__global__ void rms2048_k(const unsigned short* __restrict__ in,
                          const float* __restrict__ w,
                          unsigned short* __restrict__ out) {
  int t = blockIdx.x;
  int base = threadIdx.x * 8;
  union { uint4 q; unsigned short u[8]; } vv;
  vv.q = *(const uint4*)(in + (size_t)t * DINNER + base);
  float f[8];
  float ss = 0.f;
#pragma unroll
  for (int j = 0; j < 8; ++j) { f[j] = b2f(vv.u[j]); ss += f[j] * f[j]; }
#pragma unroll
  for (int o = 32; o > 0; o >>= 1) ss += __shfl_xor(ss, o, 64);
  __shared__ float red[4];
  if ((threadIdx.x & 63) == 0) red[threadIdx.x >> 6] = ss;
  __syncthreads();
  ss = red[0] + red[1] + red[2] + red[3];
  float scale = rsqrtf(ss * (1.f / DINNER) + EPS_F);
#pragma unroll
  for (int j = 0; j < 8; ++j)
    out[(size_t)t * DINNER + base + j] = f2b(f[j] * scale * w[base + j]);
}

// ---------------- final RMSNorm over 1024 ----------------
__global__ void rmsfinal_k(const float* __restrict__ hf,
                           const float* __restrict__ w,
                           unsigned short* __restrict__ out) {
  int t = blockIdx.x;
  int base = threadIdx.x * 4;
  float4 v = *(const float4*)(hf + (size_t)t * DIM + base);
  float ss = v.x * v.x + v.y * v.y + v.z * v.z + v.w * v.w;
#pragma unroll
  for (int o = 32; o > 0; o >>= 1) ss += __shfl_xor(ss, o, 64);
  __shared__ float red[4];
  if ((threadIdx.x & 63) == 0) red[threadIdx.x >> 6] = ss;
  __syncthreads();
  ss = red[0] + red[1] + red[2] + red[3];
  float scale = rsqrtf(ss * (1.f / DIM) + EPS_F);
  out[(size_t)t * DIM + base + 0] = f2b(v.x * scale * w[base + 0]);
  out[(size_t)t * DIM + base + 1] = f2b(v.y * scale * w[base + 1]);
  out[(size_t)t * DIM + base + 2] = f2b(v.z * scale * w[base + 2]);
  out[(size_t)t * DIM + base + 3] = f2b(v.w * scale * w[base + 3]);
}

extern "C" void kernel_launch(void* const* d_in, const int* in_sizes, int n_in,
                              void* d_out, int out_size, void* d_ws, size_t ws_size,
                              hipStream_t stream) {
  const int*   x    = (const int*)d_in[0];
  const float* emb  = (const float*)d_in[1];
  const float* Wp   = (const float*)d_in[2];
  const float* cw   = (const float*)d_in[3];
  const float* cb   = (const float*)d_in[4];
  const float* dtb  = (const float*)d_in[5];
  const float* alog = (const float*)d_in[6];
  const float* Dw   = (const float*)d_in[7];
  const float* gw   = (const float*)d_in[8];
  const float* Wo   = (const float*)d_in[9];
  const float* fnw  = (const float*)d_in[10];

  char* w = (char*)d_ws;
  auto alloc = [&](size_t bytes) {
    char* p = w; w += (bytes + 255) & ~(size_t)255; return p;
  };
  float* h_f32          = (float*)alloc((size_t)BT * DIM * 4);
  unsigned short* hb    = (unsigned short*)alloc((size_t)BT * DIM * 2);
  unsigned short* zx    = (unsigned short*)alloc((size_t)BT * DINPROJ * 2);
  float* dtraw          = (float*)alloc((size_t)BT * NHEADS * 4);
  float* dtf            = (float*)alloc((size_t)BT * NHEADS * 4);
  float* lnAf           = (float*)alloc((size_t)BT * NHEADS * 4);
  unsigned short* xbc   = (unsigned short*)alloc((size_t)BT * CONVCH * 2);
  unsigned short* bcb   = (unsigned short*)alloc((size_t)BT * 256 * 2);
  unsigned short* SL    = (unsigned short*)alloc((size_t)1024 * 64 * 128 * 2);
  unsigned short* y1buf = (unsigned short*)alloc((size_t)1024 * 64 * 64 * 2);
  float* dtot           = (float*)alloc((size_t)1024 * 4);
  unsigned short* yg    = (unsigned short*)alloc((size_t)BT * DINNER * 2);
  unsigned short* yn    = (unsigned short*)alloc((size_t)BT * DINNER * 2);
  unsigned short* hn    = (unsigned short*)alloc((size_t)BT * DIM * 2);
  unsigned short* Wp_b  = (unsigned short*)alloc((size_t)2 * DINPROJ * DIM * 2);
  unsigned short* Wo_b  = (unsigned short*)alloc((size_t)2 * DIM * DINNER * 2);
  unsigned short* emb_b = (unsigned short*)alloc((size_t)256 * DIM * 2 + 256);

  {
    int nWp = 2 * DINPROJ * DIM;
    int nWo = 2 * DIM * DINNER;
    int nEm = 256 * DIM;
    cvt_k<<<(nWp / 4 + 255) / 256, 256, 0, stream>>>(Wp, Wp_b, nWp);
    cvt_k<<<(nWo / 4 + 255) / 256, 256, 0, stream>>>(Wo, Wo_b, nWo);
    cvt_k<<<(nEm / 4 + 255) / 256, 256, 0, stream>>>(emb, emb_b, nEm);
  }

  embed_k<<<BT, 256, 0, stream>>>(x, emb, h_f32, hb);

  for (int l = 0; l < 2; ++l) {
    const unsigned short* Wpl = Wp_b + (size_t)l * DINPROJ * DIM;
    const unsigned short* Wol = Wo_b + (size_t)l * DIM * DINNER;
    const float* cwl   = cw + (size_t)l * CONVCH * 4;
    const float* cbl   = cb + (size_t)l * CONVCH;
    const float* dtbl  = dtb + l * NHEADS;
    const float* alogl = alog + l * NHEADS;
    const float* Dwl   = Dw + l * NHEADS;
    const float* gwl   = gw + (size_t)l * DINNER;

    gemm_bt<0, 128, 128><<<dim3(35, 16), 256, 0, stream>>>(hb, Wpl, BT, DINPROJ, DIM, zx, dtraw, nullptr);
    conv_k<<<BT, 256, 0, stream>>>(zx, cwl, cbl, xbc, bcb, dtraw, dtbl, alogl, dtf, lnAf);
    ssd_intra<<<1024, 256, 0, stream>>>(bcb, xbc, dtf, lnAf, y1buf, SL, dtot);
    ssd_state<<<512, 256, 0, stream>>>(SL, dtot);
    ssd_inter<<<1024, 256, 0, stream>>>(bcb, SL, y1buf, xbc, zx, lnAf, Dwl, yg);
    rms2048_k<<<BT, 256, 0, stream>>>(yg, gwl, yn);
    gemm_bt<1, 64, 64><<<dim3(16, 32), 256, 0, stream>>>(yn, Wol, BT, DIM, DINNER, nullptr, h_f32, hb);
  }

  rmsfinal_k<<<BT, 256, 0, stream>>>(h_f32, fnw, hn);
  gemm_bt<2, 64, 64><<<dim3(4, 32), 256, 0, stream>>>(hn, emb_b, BT, 256, DIM,
                                                      nullptr, (float*)d_out, nullptr);
}